// Round 13
// baseline (405.567 us; speedup 1.0000x reference)
//
#include <hip/hip_runtime.h>
#include <stdint.h>
#include <math.h>

using short8   = __attribute__((ext_vector_type(8))) short;
using ushort4v = __attribute__((ext_vector_type(4))) unsigned short;
using f32x4    = __attribute__((ext_vector_type(4))) float;
using uint4v   = __attribute__((ext_vector_type(4))) unsigned int;

#define B_ 2
#define S_ 64
#define K_ 64
#define D_ 256
#define C_ 32
#define N_ 4096  /* S_*K_ */
#define LOG2E 1.4426950408889634f

__device__ __forceinline__ float b2f(unsigned short u) {
    unsigned int v = ((unsigned int)u) << 16;
    return __builtin_bit_cast(float, v);
}
__device__ __forceinline__ unsigned short f2b(float f) {   // RNE f32->bf16
    unsigned int x = __builtin_bit_cast(unsigned int, f);
    x += 0x7fffu + ((x >> 16) & 1u);
    return (unsigned short)(x >> 16);
}
// pack two f32 -> bf16x2 (a low, b high), RNE, pure ALU (m240)
__device__ __forceinline__ unsigned int pk2(float a, float b) {
    unsigned int xa = __builtin_bit_cast(unsigned int, a);
    unsigned int xb = __builtin_bit_cast(unsigned int, b);
    xa += 0x7fffu + ((xa >> 16) & 1u);
    xb += 0x7fffu + ((xb >> 16) & 1u);
    return (xa >> 16) | (xb & 0xffff0000u);
}

// ---------------------------------------------------------------------------
// Kernel 0: W/bias pre-convert. oc 0-31 Q (x log2e), 32-63 K, 64-319 V.
// ---------------------------------------------------------------------------
__global__ __launch_bounds__(256) void wcvt_kernel(
    const float* __restrict__ Wq, const float* __restrict__ bq,
    const float* __restrict__ Wk, const float* __restrict__ bk,
    const float* __restrict__ Wv, const float* __restrict__ bv,
    unsigned short* __restrict__ Wh, unsigned short* __restrict__ Wl,
    float* __restrict__ bcat)
{
    int oc = blockIdx.x;            // 0..319
    int d  = threadIdx.x;           // 0..255
    float w;
    if (oc < 32)       w = Wq[oc * 256 + d] * LOG2E;
    else if (oc < 64)  w = Wk[(oc - 32) * 256 + d];
    else               w = Wv[(oc - 64) * 256 + d];
    unsigned short h = f2b(w);
    Wh[oc * 256 + d] = h;
    Wl[oc * 256 + d] = f2b(w - b2f(h));
    if (d == 0) {
        float bb;
        if (oc < 32)      bb = bq[oc] * LOG2E;
        else if (oc < 64) bb = bk[oc - 32];
        else              bb = bv[oc - 64];
        bcat[oc] = bb;
    }
}

// ---------------------------------------------------------------------------
// Kernel 1: QKV projections (unchanged from R12). Q,K [B][N][C] hi/lo;
// V chunk-interleaved [B][N/32][D][32], slot-permuted in-chunk
// (s = 8*((j&15)>>2) + ((j&16)>>2) + (j&3)) to match attn's register-P.
// ---------------------------------------------------------------------------
__global__ __launch_bounds__(256) void qkv_kernel(
    const float* __restrict__ x,
    const unsigned short* __restrict__ Wh, const unsigned short* __restrict__ Wl,
    const float* __restrict__ bcat,
    unsigned short* __restrict__ Qh, unsigned short* __restrict__ Ql,
    unsigned short* __restrict__ Kh, unsigned short* __restrict__ Kl,
    unsigned short* __restrict__ Vm)
{
    __shared__ unsigned short lxh[16 * 256];   // [tok][d] bf16-hi, swizzled
    __shared__ unsigned short lxl[16 * 256];   // bf16-lo

    int tid = threadIdx.x;
    int bid = blockIdx.x;
    int b  = bid >> 8;
    int n0 = (bid & 255) << 4;

    {
        int tt = tid >> 4, dg0 = (tid & 15) * 16;
        int n = n0 + tt;
        int s = n & 63, kk = n >> 6;
        const float* xr = x + (((size_t)(b * S_ + s)) * K_ + kk) * D_ + dg0;
        short8 h0, l0, h1, l1;
#pragma unroll
        for (int e = 0; e < 8; ++e) {
            float v = xr[e];
            unsigned short hh = f2b(v);
            h0[e] = (short)hh; l0[e] = (short)f2b(v - b2f(hh));
        }
#pragma unroll
        for (int e = 0; e < 8; ++e) {
            float v = xr[8 + e];
            unsigned short hh = f2b(v);
            h1[e] = (short)hh; l1[e] = (short)f2b(v - b2f(hh));
        }
        int m0 = dg0 >> 3;
        int sw0 = ((m0 ^ (tt & 7)) << 3);
        int sw1 = (((m0 + 1) ^ (tt & 7)) << 3);
        *(short8*)(lxh + tt * 256 + sw0) = h0;
        *(short8*)(lxh + tt * 256 + sw1) = h1;
        *(short8*)(lxl + tt * 256 + sw0) = l0;
        *(short8*)(lxl + tt * 256 + sw1) = l1;
    }
    __syncthreads();

    int wave = tid >> 6, lane = tid & 63;
    int col = lane & 15, g = lane >> 4;

#pragma unroll
    for (int i = 0; i < 5; ++i) {
        int ct = wave + i * 4;                   // 0..19
        int oc0 = ct * 16;
        const unsigned short* whr = Wh + (size_t)(oc0 + col) * 256;
        const unsigned short* wlr = Wl + (size_t)(oc0 + col) * 256;
        f32x4 acc = {0.f, 0.f, 0.f, 0.f};

        if (ct < 4) {                            // Q/K: split-bf16 3-chain
#pragma unroll
            for (int dc = 0; dc < 8; ++dc) {
                int sw = (((dc * 4 + g) ^ (col & 7)) << 3);
                short8 xh8 = *(const short8*)(lxh + col * 256 + sw);
                short8 xl8 = *(const short8*)(lxl + col * 256 + sw);
                short8 wh8 = *(const short8*)(whr + dc * 32 + g * 8);
                short8 wl8 = *(const short8*)(wlr + dc * 32 + g * 8);
                acc = __builtin_amdgcn_mfma_f32_16x16x32_bf16(xl8, wh8, acc, 0, 0, 0);
                acc = __builtin_amdgcn_mfma_f32_16x16x32_bf16(xh8, wl8, acc, 0, 0, 0);
                acc = __builtin_amdgcn_mfma_f32_16x16x32_bf16(xh8, wh8, acc, 0, 0, 0);
            }
            float bb = bcat[oc0 + col];
            unsigned short* Th = (ct < 2) ? Qh : Kh;
            unsigned short* Tl = (ct < 2) ? Ql : Kl;
            int c0 = (ct & 1) * 16;
#pragma unroll
            for (int r = 0; r < 4; ++r) {
                int tok = n0 + g * 4 + r;
                float v = acc[r] + bb;
                unsigned short hh = f2b(v);
                size_t idx = ((size_t)b * N_ + tok) * C_ + c0 + col;
                Th[idx] = hh;
                Tl[idx] = f2b(v - b2f(hh));
            }
        } else {                                 // V: single bf16
#pragma unroll
            for (int dc = 0; dc < 8; ++dc) {
                int sw = (((dc * 4 + g) ^ (col & 7)) << 3);
                short8 xh8 = *(const short8*)(lxh + col * 256 + sw);
                short8 wh8 = *(const short8*)(whr + dc * 32 + g * 8);
                acc = __builtin_amdgcn_mfma_f32_16x16x32_bf16(xh8, wh8, acc, 0, 0, 0);
            }
            float bb = bcat[oc0 + col];
            int c0 = oc0 - 64;
            ushort4v st;
#pragma unroll
            for (int r = 0; r < 4; ++r) st[r] = f2b(acc[r] + bb);
            int tok0 = n0 + g * 4;
            int s0 = 8 * g + ((n0 & 16) >> 2);   // slot-permuted in-chunk pos
            size_t vaddr = (((size_t)b * (N_ / 32) + (tok0 >> 5)) * D_ + c0 + col) * 32
                         + s0;
            *(ushort4v*)(Vm + vaddr) = st;
        }
    }
}

// ---------------------------------------------------------------------------
// Kernel 2: FUSED flash attention + epilogue. 256 blocks x 16 waves
// (4 waves/SIMD -- 2x the TLP of R12's 512-thread version). Block = 32
// queries x ALL 4096 keys: waves = 2 d-halves x 8 key-slices (16 iters of
// 32 keys each; per-wave body identical to R12's verified loop: register-
// only P via slot-permuted V, sched_barrier-pinned prefetch, exp2 softmax).
// End: LDS atomicAdd combine (R9 pattern) + in-block epilogue
// (1/l, gamma, residual, permuted store) -- no O_part, no epi kernel.
// XCD swizzle: b=(bid&7)>>2 -> each XCD serves one batch (~3MB L2-resident);
// qt = (bid>>3)*4 + (bid&3) (bijective).
// ---------------------------------------------------------------------------
__global__ __launch_bounds__(1024, 4) void attn_kernel(
    const unsigned short* __restrict__ Qh, const unsigned short* __restrict__ Ql,
    const unsigned short* __restrict__ Kh, const unsigned short* __restrict__ Kl,
    const unsigned short* __restrict__ Vm, const float* __restrict__ x,
    const float* __restrict__ gamma_p, float* __restrict__ out)
{
    __shared__ float accs[D_ * 33];   // [d][q] stride 33, 33.8 KB
    __shared__ float lsum[32];

    int tid  = threadIdx.x;
    int wave = tid >> 6;
    int lane = tid & 63;
    int col = lane & 15, g = lane >> 4;
    int dh = wave & 1;            // d-half 0..1
    int ks = wave >> 1;           // key-slice 0..7
    int dbase = dh * 128;
    int jbase = ks * (N_ / 8);    // 512 keys per wave

    int bid = blockIdx.x;
    int b  = (bid & 7) >> 2;                  // XCD -> batch
    int qt = (bid >> 3) * 4 + (bid & 3);      // 0..127, bijective
    int q0 = qt * 32;

    for (int i = tid; i < D_ * 33; i += 1024) accs[i] = 0.f;
    if (tid < 32) lsum[tid] = 0.f;
    __syncthreads();

    size_t qoff0 = ((size_t)b * N_ + q0 + col) * C_ + g * 8;
    size_t qoff1 = ((size_t)b * N_ + q0 + 16 + col) * C_ + g * 8;
    short8 qfh0 = *(const short8*)(Qh + qoff0);
    short8 qfl0 = *(const short8*)(Ql + qoff0);
    short8 qfh1 = *(const short8*)(Qh + qoff1);
    short8 qfl1 = *(const short8*)(Ql + qoff1);

    f32x4 acc[2][8];
#pragma unroll
    for (int qs = 0; qs < 2; ++qs)
#pragma unroll
        for (int dt = 0; dt < 8; ++dt) acc[qs][dt] = (f32x4){0.f, 0.f, 0.f, 0.f};
    float l_run0 = 0.f, l_run1 = 0.f;

    const unsigned short* kbh = Kh + (size_t)b * N_ * C_;
    const unsigned short* kbl = Kl + (size_t)b * N_ * C_;
    const unsigned short* vb  = Vm + (size_t)b * N_ * D_;   // [N/32][D][32]

    auto kaddr0 = [&](int it) { return (size_t)(jbase + it * 32 + col) * C_ + g * 8; };
    auto kaddr1 = [&](int it) { return (size_t)(jbase + it * 32 + 16 + col) * C_ + g * 8; };
    auto vaddr  = [&](int it) {
        return (size_t)((jbase >> 5) + it) * (D_ * 32) + (size_t)(dbase + col) * 32 + g * 8;
    };

    // prologue: K(0), V(0)
    short8 kh0 = *(const short8*)(kbh + kaddr0(0));
    short8 kl0 = *(const short8*)(kbl + kaddr0(0));
    short8 kh1 = *(const short8*)(kbh + kaddr1(0));
    short8 kl1 = *(const short8*)(kbl + kaddr1(0));
    short8 vcur[8];
    {
        const unsigned short* vp = vb + vaddr(0);
#pragma unroll
        for (int dt = 0; dt < 8; ++dt)
            vcur[dt] = *(const short8*)(vp + dt * (16 * 32));
    }

    for (int it = 0; it < 16; ++it) {
        // issue next iteration's K and V loads, then PIN them above compute
        short8 nkh0, nkl0, nkh1, nkl1, vnxt[8];
        int itn = (it + 1 < 16) ? it + 1 : 0;
        nkh0 = *(const short8*)(kbh + kaddr0(itn));
        nkl0 = *(const short8*)(kbl + kaddr0(itn));
        nkh1 = *(const short8*)(kbh + kaddr1(itn));
        nkl1 = *(const short8*)(kbl + kaddr1(itn));
        {
            const unsigned short* vp = vb + vaddr(itn);
#pragma unroll
            for (int dt = 0; dt < 8; ++dt)
                vnxt[dt] = *(const short8*)(vp + dt * (16 * 32));
        }
        __builtin_amdgcn_sched_barrier(0);   // loads stay issued up here

        // QK^T (split-bf16 3-chain): D[key][q], exp2-domain scores
        f32x4 z = {0.f, 0.f, 0.f, 0.f};
        f32x4 s00 = __builtin_amdgcn_mfma_f32_16x16x32_bf16(kl0, qfh0, z, 0, 0, 0);
        s00 = __builtin_amdgcn_mfma_f32_16x16x32_bf16(kh0, qfl0, s00, 0, 0, 0);
        s00 = __builtin_amdgcn_mfma_f32_16x16x32_bf16(kh0, qfh0, s00, 0, 0, 0);
        f32x4 s01 = __builtin_amdgcn_mfma_f32_16x16x32_bf16(kl1, qfh0, z, 0, 0, 0);
        s01 = __builtin_amdgcn_mfma_f32_16x16x32_bf16(kh1, qfl0, s01, 0, 0, 0);
        s01 = __builtin_amdgcn_mfma_f32_16x16x32_bf16(kh1, qfh0, s01, 0, 0, 0);
        f32x4 s10 = __builtin_amdgcn_mfma_f32_16x16x32_bf16(kl0, qfh1, z, 0, 0, 0);
        s10 = __builtin_amdgcn_mfma_f32_16x16x32_bf16(kh0, qfl1, s10, 0, 0, 0);
        s10 = __builtin_amdgcn_mfma_f32_16x16x32_bf16(kh0, qfh1, s10, 0, 0, 0);
        f32x4 s11 = __builtin_amdgcn_mfma_f32_16x16x32_bf16(kl1, qfh1, z, 0, 0, 0);
        s11 = __builtin_amdgcn_mfma_f32_16x16x32_bf16(kh1, qfl1, s11, 0, 0, 0);
        s11 = __builtin_amdgcn_mfma_f32_16x16x32_bf16(kh1, qfh1, s11, 0, 0, 0);

        // p = exp2(s'); |s'| <~50, clamp 80 is pure safety
        float pa[4], pc[4], pe[4], pg[4];
#pragma unroll
        for (int r = 0; r < 4; ++r) {
            pa[r] = exp2f(fminf(s00[r], 80.f));
            pc[r] = exp2f(fminf(s01[r], 80.f));
            pe[r] = exp2f(fminf(s10[r], 80.f));
            pg[r] = exp2f(fminf(s11[r], 80.f));
        }
        l_run0 += (pa[0] + pa[1]) + (pa[2] + pa[3]) + (pc[0] + pc[1]) + (pc[2] + pc[3]);
        l_run1 += (pe[0] + pe[1]) + (pe[2] + pe[3]) + (pg[0] + pg[1]) + (pg[2] + pg[3]);

        // pack P straight into PV B-fragments (slot-permuted; zero shuffle)
        uint4v u0, u1;
        u0[0] = pk2(pa[0], pa[1]); u0[1] = pk2(pa[2], pa[3]);
        u0[2] = pk2(pc[0], pc[1]); u0[3] = pk2(pc[2], pc[3]);
        u1[0] = pk2(pe[0], pe[1]); u1[1] = pk2(pe[2], pe[3]);
        u1[2] = pk2(pg[0], pg[1]); u1[3] = pk2(pg[2], pg[3]);
        short8 pf0 = __builtin_bit_cast(short8, u0);
        short8 pf1 = __builtin_bit_cast(short8, u1);

        // PV on own d-half (V stored with matching slot permutation)
#pragma unroll
        for (int dt = 0; dt < 8; ++dt) {
            acc[0][dt] = __builtin_amdgcn_mfma_f32_16x16x32_bf16(vcur[dt], pf0, acc[0][dt], 0, 0, 0);
            acc[1][dt] = __builtin_amdgcn_mfma_f32_16x16x32_bf16(vcur[dt], pf1, acc[1][dt], 0, 0, 0);
        }

        kh0 = nkh0; kl0 = nkl0; kh1 = nkh1; kl1 = nkl1;
#pragma unroll
        for (int dt = 0; dt < 8; ++dt) vcur[dt] = vnxt[dt];
    }

    // final l reduction across the 4 g-groups
    l_run0 += __shfl_xor(l_run0, 16); l_run0 += __shfl_xor(l_run0, 32);
    l_run1 += __shfl_xor(l_run1, 16); l_run1 += __shfl_xor(l_run1, 32);

    // combine partials across the 16 waves (plain sums: no-max softmax)
#pragma unroll
    for (int qs = 0; qs < 2; ++qs)
#pragma unroll
        for (int dt = 0; dt < 8; ++dt)
#pragma unroll
            for (int r = 0; r < 4; ++r) {
                int d = dbase + dt * 16 + g * 4 + r;
                atomicAdd(&accs[d * 33 + qs * 16 + col], acc[qs][dt][r]);
            }
    if (dh == 0 && lane < 16) {          // dh=0 twin of each ks counts l once
        atomicAdd(&lsum[col], l_run0);
        atomicAdd(&lsum[16 + col], l_run1);
    }
    __syncthreads();

    // fused epilogue: 1024 threads cover 32q x 256d; thread -> (q, 8-d run)
    int qi = tid >> 5;             // 0..31
    int d0 = (tid & 31) * 8;
    int n = q0 + qi;
    int s = n & (S_ - 1), kk = n >> 6;
    const float* xrow = x + (((size_t)(b * S_ + s)) * K_ + kk) * D_;
    float* orow = out + (((size_t)(b * S_ + s)) * K_ + kk) * D_;
    float inv_l = 1.0f / lsum[qi];
    float gam = gamma_p[0];
#pragma unroll
    for (int k = 0; k < 8; k += 4) {
        f32x4 xv = *(const f32x4*)(xrow + d0 + k);
        f32x4 ov;
#pragma unroll
        for (int e = 0; e < 4; ++e)
            ov[e] = gam * accs[(d0 + k + e) * 33 + qi] * inv_l + xv[e];
        *(f32x4*)(orow + d0 + k) = ov;
    }
}

extern "C" void kernel_launch(void* const* d_in, const int* in_sizes, int n_in,
                              void* d_out, int out_size, void* d_ws, size_t ws_size,
                              hipStream_t stream) {
    const float* x  = (const float*)d_in[0];
    const float* Wq = (const float*)d_in[1];
    const float* bq = (const float*)d_in[2];
    const float* Wk = (const float*)d_in[3];
    const float* bk = (const float*)d_in[4];
    const float* Wv = (const float*)d_in[5];
    const float* bv = (const float*)d_in[6];
    const float* gm = (const float*)d_in[7];

    char* ws = (char*)d_ws;
    unsigned short* Wh   = (unsigned short*)(ws);                 // 160KB
    unsigned short* Wl   = (unsigned short*)(ws + 0x40000);       // 160KB
    float*          bcat = (float*)         (ws + 0x80000);       // 1.3KB
    unsigned short* Qh   = (unsigned short*)(ws + 0x100000);      // 512KB
    unsigned short* Ql   = (unsigned short*)(ws + 0x180000);
    unsigned short* Kh   = (unsigned short*)(ws + 0x200000);
    unsigned short* Kl   = (unsigned short*)(ws + 0x280000);
    unsigned short* Vm   = (unsigned short*)(ws + 0x300000);      // 4MB
    float* o = (float*)d_out;

    wcvt_kernel<<<320, 256, 0, stream>>>(Wq, bq, Wk, bk, Wv, bv, Wh, Wl, bcat);
    qkv_kernel<<<512, 256, 0, stream>>>(x, Wh, Wl, bcat, Qh, Ql, Kh, Kl, Vm);
    attn_kernel<<<256, 1024, 0, stream>>>(Qh, Ql, Kh, Kl, Vm, x, gm, o);
}

// Round 14
// 114.828 us; speedup vs baseline: 3.5320x; 3.5320x over previous
//
#include <hip/hip_runtime.h>
#include <stdint.h>
#include <math.h>

using short8   = __attribute__((ext_vector_type(8))) short;
using ushort4v = __attribute__((ext_vector_type(4))) unsigned short;
using f32x4    = __attribute__((ext_vector_type(4))) float;
using uint4v   = __attribute__((ext_vector_type(4))) unsigned int;

#define B_ 2
#define S_ 64
#define K_ 64
#define D_ 256
#define C_ 32
#define N_ 4096  /* S_*K_ */
#define LOG2E 1.4426950408889634f

__device__ __forceinline__ float b2f(unsigned short u) {
    unsigned int v = ((unsigned int)u) << 16;
    return __builtin_bit_cast(float, v);
}
__device__ __forceinline__ unsigned short f2b(float f) {   // RNE f32->bf16
    unsigned int x = __builtin_bit_cast(unsigned int, f);
    x += 0x7fffu + ((x >> 16) & 1u);
    return (unsigned short)(x >> 16);
}
// pack two f32 -> bf16x2 (a low, b high), RNE, pure ALU (m240)
__device__ __forceinline__ unsigned int pk2(float a, float b) {
    unsigned int xa = __builtin_bit_cast(unsigned int, a);
    unsigned int xb = __builtin_bit_cast(unsigned int, b);
    xa += 0x7fffu + ((xa >> 16) & 1u);
    xb += 0x7fffu + ((xb >> 16) & 1u);
    return (xa >> 16) | (xb & 0xffff0000u);
}

// ---------------------------------------------------------------------------
// Kernel 0: W/bias pre-convert. oc 0-31 Q (x log2e), 32-63 K, 64-319 V.
// ---------------------------------------------------------------------------
__global__ __launch_bounds__(256) void wcvt_kernel(
    const float* __restrict__ Wq, const float* __restrict__ bq,
    const float* __restrict__ Wk, const float* __restrict__ bk,
    const float* __restrict__ Wv, const float* __restrict__ bv,
    unsigned short* __restrict__ Wh, unsigned short* __restrict__ Wl,
    float* __restrict__ bcat)
{
    int oc = blockIdx.x;            // 0..319
    int d  = threadIdx.x;           // 0..255
    float w;
    if (oc < 32)       w = Wq[oc * 256 + d] * LOG2E;
    else if (oc < 64)  w = Wk[(oc - 32) * 256 + d];
    else               w = Wv[(oc - 64) * 256 + d];
    unsigned short h = f2b(w);
    Wh[oc * 256 + d] = h;
    Wl[oc * 256 + d] = f2b(w - b2f(h));
    if (d == 0) {
        float bb;
        if (oc < 32)      bb = bq[oc] * LOG2E;
        else if (oc < 64) bb = bk[oc - 32];
        else              bb = bv[oc - 64];
        bcat[oc] = bb;
    }
}

// ---------------------------------------------------------------------------
// Kernel 1: QKV projections (unchanged, verified). Q,K [B][N][C] hi/lo;
// V chunk-interleaved [B][N/32][D][32], slot-permuted in-chunk
// (s = 8*((j&15)>>2) + ((j&16)>>2) + (j&3)) to match attn's register-P.
// ---------------------------------------------------------------------------
__global__ __launch_bounds__(256) void qkv_kernel(
    const float* __restrict__ x,
    const unsigned short* __restrict__ Wh, const unsigned short* __restrict__ Wl,
    const float* __restrict__ bcat,
    unsigned short* __restrict__ Qh, unsigned short* __restrict__ Ql,
    unsigned short* __restrict__ Kh, unsigned short* __restrict__ Kl,
    unsigned short* __restrict__ Vm)
{
    __shared__ unsigned short lxh[16 * 256];   // [tok][d] bf16-hi, swizzled
    __shared__ unsigned short lxl[16 * 256];   // bf16-lo

    int tid = threadIdx.x;
    int bid = blockIdx.x;
    int b  = bid >> 8;
    int n0 = (bid & 255) << 4;

    {
        int tt = tid >> 4, dg0 = (tid & 15) * 16;
        int n = n0 + tt;
        int s = n & 63, kk = n >> 6;
        const float* xr = x + (((size_t)(b * S_ + s)) * K_ + kk) * D_ + dg0;
        short8 h0, l0, h1, l1;
#pragma unroll
        for (int e = 0; e < 8; ++e) {
            float v = xr[e];
            unsigned short hh = f2b(v);
            h0[e] = (short)hh; l0[e] = (short)f2b(v - b2f(hh));
        }
#pragma unroll
        for (int e = 0; e < 8; ++e) {
            float v = xr[8 + e];
            unsigned short hh = f2b(v);
            h1[e] = (short)hh; l1[e] = (short)f2b(v - b2f(hh));
        }
        int m0 = dg0 >> 3;
        int sw0 = ((m0 ^ (tt & 7)) << 3);
        int sw1 = (((m0 + 1) ^ (tt & 7)) << 3);
        *(short8*)(lxh + tt * 256 + sw0) = h0;
        *(short8*)(lxh + tt * 256 + sw1) = h1;
        *(short8*)(lxl + tt * 256 + sw0) = l0;
        *(short8*)(lxl + tt * 256 + sw1) = l1;
    }
    __syncthreads();

    int wave = tid >> 6, lane = tid & 63;
    int col = lane & 15, g = lane >> 4;

#pragma unroll
    for (int i = 0; i < 5; ++i) {
        int ct = wave + i * 4;                   // 0..19
        int oc0 = ct * 16;
        const unsigned short* whr = Wh + (size_t)(oc0 + col) * 256;
        const unsigned short* wlr = Wl + (size_t)(oc0 + col) * 256;
        f32x4 acc = {0.f, 0.f, 0.f, 0.f};

        if (ct < 4) {                            // Q/K: split-bf16 3-chain
#pragma unroll
            for (int dc = 0; dc < 8; ++dc) {
                int sw = (((dc * 4 + g) ^ (col & 7)) << 3);
                short8 xh8 = *(const short8*)(lxh + col * 256 + sw);
                short8 xl8 = *(const short8*)(lxl + col * 256 + sw);
                short8 wh8 = *(const short8*)(whr + dc * 32 + g * 8);
                short8 wl8 = *(const short8*)(wlr + dc * 32 + g * 8);
                acc = __builtin_amdgcn_mfma_f32_16x16x32_bf16(xl8, wh8, acc, 0, 0, 0);
                acc = __builtin_amdgcn_mfma_f32_16x16x32_bf16(xh8, wl8, acc, 0, 0, 0);
                acc = __builtin_amdgcn_mfma_f32_16x16x32_bf16(xh8, wh8, acc, 0, 0, 0);
            }
            float bb = bcat[oc0 + col];
            unsigned short* Th = (ct < 2) ? Qh : Kh;
            unsigned short* Tl = (ct < 2) ? Ql : Kl;
            int c0 = (ct & 1) * 16;
#pragma unroll
            for (int r = 0; r < 4; ++r) {
                int tok = n0 + g * 4 + r;
                float v = acc[r] + bb;
                unsigned short hh = f2b(v);
                size_t idx = ((size_t)b * N_ + tok) * C_ + c0 + col;
                Th[idx] = hh;
                Tl[idx] = f2b(v - b2f(hh));
            }
        } else {                                 // V: single bf16
#pragma unroll
            for (int dc = 0; dc < 8; ++dc) {
                int sw = (((dc * 4 + g) ^ (col & 7)) << 3);
                short8 xh8 = *(const short8*)(lxh + col * 256 + sw);
                short8 wh8 = *(const short8*)(whr + dc * 32 + g * 8);
                acc = __builtin_amdgcn_mfma_f32_16x16x32_bf16(xh8, wh8, acc, 0, 0, 0);
            }
            float bb = bcat[oc0 + col];
            int c0 = oc0 - 64;
            ushort4v st;
#pragma unroll
            for (int r = 0; r < 4; ++r) st[r] = f2b(acc[r] + bb);
            int tok0 = n0 + g * 4;
            int s0 = 8 * g + ((n0 & 16) >> 2);   // slot-permuted in-chunk pos
            size_t vaddr = (((size_t)b * (N_ / 32) + (tok0 >> 5)) * D_ + c0 + col) * 32
                         + s0;
            *(ushort4v*)(Vm + vaddr) = st;
        }
    }
}

// ---------------------------------------------------------------------------
// Kernel 2: FUSED flash attention + epilogue, back in the verified R12
// register regime: 256 blocks x 512 threads, __launch_bounds__(512,2)
// (2 waves/EU -> 256-unified-reg cap; this body needs ~176. R13 lesson:
// requesting 4 waves/EU caps at 128 regs -> total spill, 1.7GB scratch).
// 8 waves = 2 d-halves x 4 key-slices (1024 keys = 32 iters each); block
// covers ALL keys for its 32 queries -> in-block LDS atomicAdd combine +
// fused epilogue (no O_part, no epi kernel). Loop body = R12 verified:
// register-only P (slot-permuted V), sched_barrier-pinned prefetch, pk2,
// exp2 softmax without clamp (|s| <= ~50 << 128 overflow).
// ---------------------------------------------------------------------------
__global__ __launch_bounds__(512, 2) void attn_kernel(
    const unsigned short* __restrict__ Qh, const unsigned short* __restrict__ Ql,
    const unsigned short* __restrict__ Kh, const unsigned short* __restrict__ Kl,
    const unsigned short* __restrict__ Vm, const float* __restrict__ x,
    const float* __restrict__ gamma_p, float* __restrict__ out)
{
    __shared__ float accs[D_ * 33];   // [d][q] stride 33, 33.8 KB
    __shared__ float lsum[32];

    int tid  = threadIdx.x;
    int wave = tid >> 6;
    int lane = tid & 63;
    int col = lane & 15, g = lane >> 4;
    int dh = wave & 1;            // d-half 0..1
    int ks = wave >> 1;           // key-slice 0..3
    int dbase = dh * 128;
    int jbase = ks * (N_ / 4);    // 1024 keys per wave

    int bid = blockIdx.x;
    int b  = (bid & 7) >> 2;                  // XCD -> batch (L2-resident)
    int qt = (bid >> 3) * 4 + (bid & 3);      // 0..127, bijective
    int q0 = qt * 32;

    for (int i = tid; i < D_ * 33; i += 512) accs[i] = 0.f;
    if (tid < 32) lsum[tid] = 0.f;
    __syncthreads();

    size_t qoff0 = ((size_t)b * N_ + q0 + col) * C_ + g * 8;
    size_t qoff1 = ((size_t)b * N_ + q0 + 16 + col) * C_ + g * 8;
    short8 qfh0 = *(const short8*)(Qh + qoff0);
    short8 qfl0 = *(const short8*)(Ql + qoff0);
    short8 qfh1 = *(const short8*)(Qh + qoff1);
    short8 qfl1 = *(const short8*)(Ql + qoff1);

    f32x4 acc[2][8];
#pragma unroll
    for (int qs = 0; qs < 2; ++qs)
#pragma unroll
        for (int dt = 0; dt < 8; ++dt) acc[qs][dt] = (f32x4){0.f, 0.f, 0.f, 0.f};
    float l_run0 = 0.f, l_run1 = 0.f;

    const unsigned short* kbh = Kh + (size_t)b * N_ * C_;
    const unsigned short* kbl = Kl + (size_t)b * N_ * C_;
    const unsigned short* vb  = Vm + (size_t)b * N_ * D_;   // [N/32][D][32]

    auto kaddr0 = [&](int it) { return (size_t)(jbase + it * 32 + col) * C_ + g * 8; };
    auto kaddr1 = [&](int it) { return (size_t)(jbase + it * 32 + 16 + col) * C_ + g * 8; };
    auto vaddr  = [&](int it) {
        return (size_t)((jbase >> 5) + it) * (D_ * 32) + (size_t)(dbase + col) * 32 + g * 8;
    };

    // prologue: K(0), V(0)
    short8 kh0 = *(const short8*)(kbh + kaddr0(0));
    short8 kl0 = *(const short8*)(kbl + kaddr0(0));
    short8 kh1 = *(const short8*)(kbh + kaddr1(0));
    short8 kl1 = *(const short8*)(kbl + kaddr1(0));
    short8 vcur[8];
    {
        const unsigned short* vp = vb + vaddr(0);
#pragma unroll
        for (int dt = 0; dt < 8; ++dt)
            vcur[dt] = *(const short8*)(vp + dt * (16 * 32));
    }

    for (int it = 0; it < 32; ++it) {
        // issue next iteration's K and V loads, then PIN them above compute
        short8 nkh0, nkl0, nkh1, nkl1, vnxt[8];
        int itn = (it + 1 < 32) ? it + 1 : 0;
        nkh0 = *(const short8*)(kbh + kaddr0(itn));
        nkl0 = *(const short8*)(kbl + kaddr0(itn));
        nkh1 = *(const short8*)(kbh + kaddr1(itn));
        nkl1 = *(const short8*)(kbl + kaddr1(itn));
        {
            const unsigned short* vp = vb + vaddr(itn);
#pragma unroll
            for (int dt = 0; dt < 8; ++dt)
                vnxt[dt] = *(const short8*)(vp + dt * (16 * 32));
        }
        __builtin_amdgcn_sched_barrier(0);   // loads stay issued up here

        // QK^T (split-bf16 3-chain): D[key][q], exp2-domain scores
        f32x4 z = {0.f, 0.f, 0.f, 0.f};
        f32x4 s00 = __builtin_amdgcn_mfma_f32_16x16x32_bf16(kl0, qfh0, z, 0, 0, 0);
        s00 = __builtin_amdgcn_mfma_f32_16x16x32_bf16(kh0, qfl0, s00, 0, 0, 0);
        s00 = __builtin_amdgcn_mfma_f32_16x16x32_bf16(kh0, qfh0, s00, 0, 0, 0);
        f32x4 s01 = __builtin_amdgcn_mfma_f32_16x16x32_bf16(kl1, qfh0, z, 0, 0, 0);
        s01 = __builtin_amdgcn_mfma_f32_16x16x32_bf16(kh1, qfl0, s01, 0, 0, 0);
        s01 = __builtin_amdgcn_mfma_f32_16x16x32_bf16(kh1, qfh0, s01, 0, 0, 0);
        f32x4 s10 = __builtin_amdgcn_mfma_f32_16x16x32_bf16(kl0, qfh1, z, 0, 0, 0);
        s10 = __builtin_amdgcn_mfma_f32_16x16x32_bf16(kh0, qfl1, s10, 0, 0, 0);
        s10 = __builtin_amdgcn_mfma_f32_16x16x32_bf16(kh0, qfh1, s10, 0, 0, 0);
        f32x4 s11 = __builtin_amdgcn_mfma_f32_16x16x32_bf16(kl1, qfh1, z, 0, 0, 0);
        s11 = __builtin_amdgcn_mfma_f32_16x16x32_bf16(kh1, qfl1, s11, 0, 0, 0);
        s11 = __builtin_amdgcn_mfma_f32_16x16x32_bf16(kh1, qfh1, s11, 0, 0, 0);

        // p = exp2(s'); |s'| <= ~50 << 128 (exp2 overflow) -- no clamp needed
        float pa[4], pc[4], pe[4], pg[4];
#pragma unroll
        for (int r = 0; r < 4; ++r) {
            pa[r] = exp2f(s00[r]);
            pc[r] = exp2f(s01[r]);
            pe[r] = exp2f(s10[r]);
            pg[r] = exp2f(s11[r]);
        }
        l_run0 += (pa[0] + pa[1]) + (pa[2] + pa[3]) + (pc[0] + pc[1]) + (pc[2] + pc[3]);
        l_run1 += (pe[0] + pe[1]) + (pe[2] + pe[3]) + (pg[0] + pg[1]) + (pg[2] + pg[3]);

        // pack P straight into PV B-fragments (slot-permuted; zero shuffle)
        uint4v u0, u1;
        u0[0] = pk2(pa[0], pa[1]); u0[1] = pk2(pa[2], pa[3]);
        u0[2] = pk2(pc[0], pc[1]); u0[3] = pk2(pc[2], pc[3]);
        u1[0] = pk2(pe[0], pe[1]); u1[1] = pk2(pe[2], pe[3]);
        u1[2] = pk2(pg[0], pg[1]); u1[3] = pk2(pg[2], pg[3]);
        short8 pf0 = __builtin_bit_cast(short8, u0);
        short8 pf1 = __builtin_bit_cast(short8, u1);

        // PV on own d-half (V stored with matching slot permutation)
#pragma unroll
        for (int dt = 0; dt < 8; ++dt) {
            acc[0][dt] = __builtin_amdgcn_mfma_f32_16x16x32_bf16(vcur[dt], pf0, acc[0][dt], 0, 0, 0);
            acc[1][dt] = __builtin_amdgcn_mfma_f32_16x16x32_bf16(vcur[dt], pf1, acc[1][dt], 0, 0, 0);
        }

        kh0 = nkh0; kl0 = nkl0; kh1 = nkh1; kl1 = nkl1;
#pragma unroll
        for (int dt = 0; dt < 8; ++dt) vcur[dt] = vnxt[dt];
    }

    // final l reduction across the 4 g-groups
    l_run0 += __shfl_xor(l_run0, 16); l_run0 += __shfl_xor(l_run0, 32);
    l_run1 += __shfl_xor(l_run1, 16); l_run1 += __shfl_xor(l_run1, 32);

    // combine partials across the 8 waves (plain sums: no-max softmax)
#pragma unroll
    for (int qs = 0; qs < 2; ++qs)
#pragma unroll
        for (int dt = 0; dt < 8; ++dt)
#pragma unroll
            for (int r = 0; r < 4; ++r) {
                int d = dbase + dt * 16 + g * 4 + r;
                atomicAdd(&accs[d * 33 + qs * 16 + col], acc[qs][dt][r]);
            }
    if (dh == 0 && lane < 16) {          // dh=0 twin of each ks counts l once
        atomicAdd(&lsum[col], l_run0);
        atomicAdd(&lsum[16 + col], l_run1);
    }
    __syncthreads();

    // fused epilogue: 512 threads cover 32q x 256d; thread -> (q, 16-d run)
    int qi = tid >> 4;             // 0..31
    int d0 = (tid & 15) * 16;
    int n = q0 + qi;
    int s = n & (S_ - 1), kk = n >> 6;
    const float* xrow = x + (((size_t)(b * S_ + s)) * K_ + kk) * D_;
    float* orow = out + (((size_t)(b * S_ + s)) * K_ + kk) * D_;
    float inv_l = 1.0f / lsum[qi];
    float gam = gamma_p[0];
#pragma unroll
    for (int k = 0; k < 16; k += 4) {
        f32x4 xv = *(const f32x4*)(xrow + d0 + k);
        f32x4 ov;
#pragma unroll
        for (int e = 0; e < 4; ++e)
            ov[e] = gam * accs[(d0 + k + e) * 33 + qi] * inv_l + xv[e];
        *(f32x4*)(orow + d0 + k) = ov;
    }
}

extern "C" void kernel_launch(void* const* d_in, const int* in_sizes, int n_in,
                              void* d_out, int out_size, void* d_ws, size_t ws_size,
                              hipStream_t stream) {
    const float* x  = (const float*)d_in[0];
    const float* Wq = (const float*)d_in[1];
    const float* bq = (const float*)d_in[2];
    const float* Wk = (const float*)d_in[3];
    const float* bk = (const float*)d_in[4];
    const float* Wv = (const float*)d_in[5];
    const float* bv = (const float*)d_in[6];
    const float* gm = (const float*)d_in[7];

    char* ws = (char*)d_ws;
    unsigned short* Wh   = (unsigned short*)(ws);                 // 160KB
    unsigned short* Wl   = (unsigned short*)(ws + 0x40000);       // 160KB
    float*          bcat = (float*)         (ws + 0x80000);       // 1.3KB
    unsigned short* Qh   = (unsigned short*)(ws + 0x100000);      // 512KB
    unsigned short* Ql   = (unsigned short*)(ws + 0x180000);
    unsigned short* Kh   = (unsigned short*)(ws + 0x200000);
    unsigned short* Kl   = (unsigned short*)(ws + 0x280000);
    unsigned short* Vm   = (unsigned short*)(ws + 0x300000);      // 4MB
    float* o = (float*)d_out;

    wcvt_kernel<<<320, 256, 0, stream>>>(Wq, bq, Wk, bk, Wv, bv, Wh, Wl, bcat);
    qkv_kernel<<<512, 256, 0, stream>>>(x, Wh, Wl, bcat, Qh, Ql, Kh, Kl, Vm);
    attn_kernel<<<256, 512, 0, stream>>>(Qh, Ql, Kh, Kl, Vm, x, gm, o);
}

// Round 15
// 84.080 us; speedup vs baseline: 4.8236x; 1.3657x over previous
//
#include <hip/hip_runtime.h>
#include <stdint.h>
#include <math.h>

using short8   = __attribute__((ext_vector_type(8))) short;
using ushort4v = __attribute__((ext_vector_type(4))) unsigned short;
using f32x4    = __attribute__((ext_vector_type(4))) float;
using uint4v   = __attribute__((ext_vector_type(4))) unsigned int;

#define B_ 2
#define S_ 64
#define K_ 64
#define D_ 256
#define C_ 32
#define N_ 4096  /* S_*K_ */
#define LOG2E 1.4426950408889634f

__device__ __forceinline__ float b2f(unsigned short u) {
    unsigned int v = ((unsigned int)u) << 16;
    return __builtin_bit_cast(float, v);
}
__device__ __forceinline__ unsigned short f2b(float f) {   // RNE f32->bf16
    unsigned int x = __builtin_bit_cast(unsigned int, f);
    x += 0x7fffu + ((x >> 16) & 1u);
    return (unsigned short)(x >> 16);
}
// pack two f32 -> bf16x2 (a low, b high), RNE, pure ALU (m240)
__device__ __forceinline__ unsigned int pk2(float a, float b) {
    unsigned int xa = __builtin_bit_cast(unsigned int, a);
    unsigned int xb = __builtin_bit_cast(unsigned int, b);
    xa += 0x7fffu + ((xa >> 16) & 1u);
    xb += 0x7fffu + ((xb >> 16) & 1u);
    return (xa >> 16) | (xb & 0xffff0000u);
}

// ---------------------------------------------------------------------------
// Kernel 0: W/bias pre-convert. oc 0-31 Q (x log2e), 32-63 K, 64-319 V.
// ---------------------------------------------------------------------------
__global__ __launch_bounds__(256) void wcvt_kernel(
    const float* __restrict__ Wq, const float* __restrict__ bq,
    const float* __restrict__ Wk, const float* __restrict__ bk,
    const float* __restrict__ Wv, const float* __restrict__ bv,
    unsigned short* __restrict__ Wh, unsigned short* __restrict__ Wl,
    float* __restrict__ bcat)
{
    int oc = blockIdx.x;            // 0..319
    int d  = threadIdx.x;           // 0..255
    float w;
    if (oc < 32)       w = Wq[oc * 256 + d] * LOG2E;
    else if (oc < 64)  w = Wk[(oc - 32) * 256 + d];
    else               w = Wv[(oc - 64) * 256 + d];
    unsigned short h = f2b(w);
    Wh[oc * 256 + d] = h;
    Wl[oc * 256 + d] = f2b(w - b2f(h));
    if (d == 0) {
        float bb;
        if (oc < 32)      bb = bq[oc] * LOG2E;
        else if (oc < 64) bb = bk[oc - 32];
        else              bb = bv[oc - 64];
        bcat[oc] = bb;
    }
}

// ---------------------------------------------------------------------------
// Kernel 1: QKV projections (verified). Q,K [B][N][C] hi/lo; V chunk-
// interleaved [B][N/32][D][32], slot-permuted in-chunk
// (s = 8*((j&15)>>2) + ((j&16)>>2) + (j&3)) to match attn's register-P.
// ---------------------------------------------------------------------------
__global__ __launch_bounds__(256) void qkv_kernel(
    const float* __restrict__ x,
    const unsigned short* __restrict__ Wh, const unsigned short* __restrict__ Wl,
    const float* __restrict__ bcat,
    unsigned short* __restrict__ Qh, unsigned short* __restrict__ Ql,
    unsigned short* __restrict__ Kh, unsigned short* __restrict__ Kl,
    unsigned short* __restrict__ Vm)
{
    __shared__ unsigned short lxh[16 * 256];   // [tok][d] bf16-hi, swizzled
    __shared__ unsigned short lxl[16 * 256];   // bf16-lo

    int tid = threadIdx.x;
    int bid = blockIdx.x;
    int b  = bid >> 8;
    int n0 = (bid & 255) << 4;

    {
        int tt = tid >> 4, dg0 = (tid & 15) * 16;
        int n = n0 + tt;
        int s = n & 63, kk = n >> 6;
        const float* xr = x + (((size_t)(b * S_ + s)) * K_ + kk) * D_ + dg0;
        short8 h0, l0, h1, l1;
#pragma unroll
        for (int e = 0; e < 8; ++e) {
            float v = xr[e];
            unsigned short hh = f2b(v);
            h0[e] = (short)hh; l0[e] = (short)f2b(v - b2f(hh));
        }
#pragma unroll
        for (int e = 0; e < 8; ++e) {
            float v = xr[8 + e];
            unsigned short hh = f2b(v);
            h1[e] = (short)hh; l1[e] = (short)f2b(v - b2f(hh));
        }
        int m0 = dg0 >> 3;
        int sw0 = ((m0 ^ (tt & 7)) << 3);
        int sw1 = (((m0 + 1) ^ (tt & 7)) << 3);
        *(short8*)(lxh + tt * 256 + sw0) = h0;
        *(short8*)(lxh + tt * 256 + sw1) = h1;
        *(short8*)(lxl + tt * 256 + sw0) = l0;
        *(short8*)(lxl + tt * 256 + sw1) = l1;
    }
    __syncthreads();

    int wave = tid >> 6, lane = tid & 63;
    int col = lane & 15, g = lane >> 4;

#pragma unroll
    for (int i = 0; i < 5; ++i) {
        int ct = wave + i * 4;                   // 0..19
        int oc0 = ct * 16;
        const unsigned short* whr = Wh + (size_t)(oc0 + col) * 256;
        const unsigned short* wlr = Wl + (size_t)(oc0 + col) * 256;
        f32x4 acc = {0.f, 0.f, 0.f, 0.f};

        if (ct < 4) {                            // Q/K: split-bf16 3-chain
#pragma unroll
            for (int dc = 0; dc < 8; ++dc) {
                int sw = (((dc * 4 + g) ^ (col & 7)) << 3);
                short8 xh8 = *(const short8*)(lxh + col * 256 + sw);
                short8 xl8 = *(const short8*)(lxl + col * 256 + sw);
                short8 wh8 = *(const short8*)(whr + dc * 32 + g * 8);
                short8 wl8 = *(const short8*)(wlr + dc * 32 + g * 8);
                acc = __builtin_amdgcn_mfma_f32_16x16x32_bf16(xl8, wh8, acc, 0, 0, 0);
                acc = __builtin_amdgcn_mfma_f32_16x16x32_bf16(xh8, wl8, acc, 0, 0, 0);
                acc = __builtin_amdgcn_mfma_f32_16x16x32_bf16(xh8, wh8, acc, 0, 0, 0);
            }
            float bb = bcat[oc0 + col];
            unsigned short* Th = (ct < 2) ? Qh : Kh;
            unsigned short* Tl = (ct < 2) ? Ql : Kl;
            int c0 = (ct & 1) * 16;
#pragma unroll
            for (int r = 0; r < 4; ++r) {
                int tok = n0 + g * 4 + r;
                float v = acc[r] + bb;
                unsigned short hh = f2b(v);
                size_t idx = ((size_t)b * N_ + tok) * C_ + c0 + col;
                Th[idx] = hh;
                Tl[idx] = f2b(v - b2f(hh));
            }
        } else {                                 // V: single bf16
#pragma unroll
            for (int dc = 0; dc < 8; ++dc) {
                int sw = (((dc * 4 + g) ^ (col & 7)) << 3);
                short8 xh8 = *(const short8*)(lxh + col * 256 + sw);
                short8 wh8 = *(const short8*)(whr + dc * 32 + g * 8);
                acc = __builtin_amdgcn_mfma_f32_16x16x32_bf16(xh8, wh8, acc, 0, 0, 0);
            }
            float bb = bcat[oc0 + col];
            int c0 = oc0 - 64;
            ushort4v st;
#pragma unroll
            for (int r = 0; r < 4; ++r) st[r] = f2b(acc[r] + bb);
            int tok0 = n0 + g * 4;
            int s0 = 8 * g + ((n0 & 16) >> 2);   // slot-permuted in-chunk pos
            size_t vaddr = (((size_t)b * (N_ / 32) + (tok0 >> 5)) * D_ + c0 + col) * 32
                         + s0;
            *(ushort4v*)(Vm + vaddr) = st;
        }
    }
}

// ---------------------------------------------------------------------------
// Kernel 2: flash attention — R12 structure restored (cross-block key-split
// keeps 4-8x intra-block K/V reuse; R14 lesson: in-block key-split = 4x L2
// traffic). 256 blocks: bid&7=(b*4+ks) per XCD; 8 waves = 4 q-quarters x
// 2 d-halves; wave = 32q x 128d x 1024 keys. Register-only P (slot-permuted
// V), exp2 softmax (no clamp), partial dump to O_part + epi kernel.
// NEW vs R12: (a) unroll-2 with named A/B register sets (no rotation movs),
// (b) wrap-free prefetch it+1 (one-past-end prefetch lands in adjacent ws
// regions, discarded) -> linear addresses, strength-reduced.
// ---------------------------------------------------------------------------
__global__ __launch_bounds__(512, 2) void attn_kernel(
    const unsigned short* __restrict__ Qh, const unsigned short* __restrict__ Ql,
    const unsigned short* __restrict__ Kh, const unsigned short* __restrict__ Kl,
    const unsigned short* __restrict__ Vm,
    float* __restrict__ O_part, float* __restrict__ lsum_part)
{
    int tid  = threadIdx.x;
    int wave = tid >> 6;
    int lane = tid & 63;
    int col = lane & 15, g = lane >> 4;
    int qq = wave >> 1;           // q-quarter 0..3
    int dh = wave & 1;            // d-half 0..1
    int dbase = dh * 128;

    int bid = blockIdx.x;
    int x7 = bid & 7;
    int b  = x7 >> 2;
    int ks = x7 & 3;
    int qt = bid >> 3;            // 0..31 (q-tile within batch)
    int q0 = qt * 128 + qq * 32;
    int jbase = ks * (N_ / 4);

    size_t qoff0 = ((size_t)b * N_ + q0 + col) * C_ + g * 8;
    size_t qoff1 = ((size_t)b * N_ + q0 + 16 + col) * C_ + g * 8;
    short8 qfh0 = *(const short8*)(Qh + qoff0);
    short8 qfl0 = *(const short8*)(Ql + qoff0);
    short8 qfh1 = *(const short8*)(Qh + qoff1);
    short8 qfl1 = *(const short8*)(Ql + qoff1);

    f32x4 acc[2][8];
#pragma unroll
    for (int qs = 0; qs < 2; ++qs)
#pragma unroll
        for (int dt = 0; dt < 8; ++dt) acc[qs][dt] = (f32x4){0.f, 0.f, 0.f, 0.f};
    float l_run0 = 0.f, l_run1 = 0.f;

    const unsigned short* kbh = Kh + (size_t)b * N_ * C_;
    const unsigned short* kbl = Kl + (size_t)b * N_ * C_;
    const unsigned short* vb  = Vm + (size_t)b * N_ * D_;   // [N/32][D][32]

    auto kaddr0 = [&](int it) { return (size_t)(jbase + it * 32 + col) * C_ + g * 8; };
    auto kaddr1 = [&](int it) { return (size_t)(jbase + it * 32 + 16 + col) * C_ + g * 8; };
    auto vaddr  = [&](int it) {
        return (size_t)(ks * 32 + it) * (D_ * 32) + (size_t)(dbase + col) * 32 + g * 8;
    };

    // prologue: K(0), V(0) into the A set
    short8 kh0A = *(const short8*)(kbh + kaddr0(0));
    short8 kl0A = *(const short8*)(kbl + kaddr0(0));
    short8 kh1A = *(const short8*)(kbh + kaddr1(0));
    short8 kl1A = *(const short8*)(kbl + kaddr1(0));
    short8 vA[8], vB[8];
    short8 kh0B, kl0B, kh1B, kl1B;
    {
        const unsigned short* vp = vb + vaddr(0);
#pragma unroll
        for (int dt = 0; dt < 8; ++dt)
            vA[dt] = *(const short8*)(vp + dt * (16 * 32));
    }

    // one iteration phase: consume CUR set, prefetch (IT+1) into NXT set.
    // IT+1 may be 32 (one past end): lands in adjacent ws regions, discarded.
#define ATTN_PHASE(IT, CKH0, CKL0, CKH1, CKL1, CV, NKH0, NKL0, NKH1, NKL1, NV)   \
    {                                                                            \
        int itn_ = (IT) + 1;                                                     \
        NKH0 = *(const short8*)(kbh + kaddr0(itn_));                             \
        NKL0 = *(const short8*)(kbl + kaddr0(itn_));                             \
        NKH1 = *(const short8*)(kbh + kaddr1(itn_));                             \
        NKL1 = *(const short8*)(kbl + kaddr1(itn_));                             \
        {                                                                        \
            const unsigned short* vp_ = vb + vaddr(itn_);                        \
            _Pragma("unroll")                                                    \
            for (int dt = 0; dt < 8; ++dt)                                       \
                NV[dt] = *(const short8*)(vp_ + dt * (16 * 32));                 \
        }                                                                        \
        __builtin_amdgcn_sched_barrier(0);  /* loads stay issued up here */      \
        f32x4 z_ = {0.f, 0.f, 0.f, 0.f};                                         \
        f32x4 s00 = __builtin_amdgcn_mfma_f32_16x16x32_bf16(CKL0, qfh0, z_, 0, 0, 0); \
        s00 = __builtin_amdgcn_mfma_f32_16x16x32_bf16(CKH0, qfl0, s00, 0, 0, 0); \
        s00 = __builtin_amdgcn_mfma_f32_16x16x32_bf16(CKH0, qfh0, s00, 0, 0, 0); \
        f32x4 s01 = __builtin_amdgcn_mfma_f32_16x16x32_bf16(CKL1, qfh0, z_, 0, 0, 0); \
        s01 = __builtin_amdgcn_mfma_f32_16x16x32_bf16(CKH1, qfl0, s01, 0, 0, 0); \
        s01 = __builtin_amdgcn_mfma_f32_16x16x32_bf16(CKH1, qfh0, s01, 0, 0, 0); \
        f32x4 s10 = __builtin_amdgcn_mfma_f32_16x16x32_bf16(CKL0, qfh1, z_, 0, 0, 0); \
        s10 = __builtin_amdgcn_mfma_f32_16x16x32_bf16(CKH0, qfl1, s10, 0, 0, 0); \
        s10 = __builtin_amdgcn_mfma_f32_16x16x32_bf16(CKH0, qfh1, s10, 0, 0, 0); \
        f32x4 s11 = __builtin_amdgcn_mfma_f32_16x16x32_bf16(CKL1, qfh1, z_, 0, 0, 0); \
        s11 = __builtin_amdgcn_mfma_f32_16x16x32_bf16(CKH1, qfl1, s11, 0, 0, 0); \
        s11 = __builtin_amdgcn_mfma_f32_16x16x32_bf16(CKH1, qfh1, s11, 0, 0, 0); \
        float pa[4], pc[4], pe[4], pg[4];                                        \
        _Pragma("unroll")                                                        \
        for (int r = 0; r < 4; ++r) {                                            \
            pa[r] = exp2f(s00[r]);                                               \
            pc[r] = exp2f(s01[r]);                                               \
            pe[r] = exp2f(s10[r]);                                               \
            pg[r] = exp2f(s11[r]);                                               \
        }                                                                        \
        l_run0 += (pa[0] + pa[1]) + (pa[2] + pa[3])                              \
                + (pc[0] + pc[1]) + (pc[2] + pc[3]);                             \
        l_run1 += (pe[0] + pe[1]) + (pe[2] + pe[3])                              \
                + (pg[0] + pg[1]) + (pg[2] + pg[3]);                             \
        uint4v u0, u1;                                                           \
        u0[0] = pk2(pa[0], pa[1]); u0[1] = pk2(pa[2], pa[3]);                    \
        u0[2] = pk2(pc[0], pc[1]); u0[3] = pk2(pc[2], pc[3]);                    \
        u1[0] = pk2(pe[0], pe[1]); u1[1] = pk2(pe[2], pe[3]);                    \
        u1[2] = pk2(pg[0], pg[1]); u1[3] = pk2(pg[2], pg[3]);                    \
        short8 pf0 = __builtin_bit_cast(short8, u0);                             \
        short8 pf1 = __builtin_bit_cast(short8, u1);                             \
        _Pragma("unroll")                                                        \
        for (int dt = 0; dt < 8; ++dt) {                                         \
            acc[0][dt] = __builtin_amdgcn_mfma_f32_16x16x32_bf16(CV[dt], pf0, acc[0][dt], 0, 0, 0); \
            acc[1][dt] = __builtin_amdgcn_mfma_f32_16x16x32_bf16(CV[dt], pf1, acc[1][dt], 0, 0, 0); \
        }                                                                        \
    }

    for (int it2 = 0; it2 < 16; ++it2) {
        int itA = it2 * 2, itB = it2 * 2 + 1;
        ATTN_PHASE(itA, kh0A, kl0A, kh1A, kl1A, vA, kh0B, kl0B, kh1B, kl1B, vB);
        ATTN_PHASE(itB, kh0B, kl0B, kh1B, kl1B, vB, kh0A, kl0A, kh1A, kl1A, vA);
    }
#undef ATTN_PHASE

    // final l reduction across the 4 g-groups
    l_run0 += __shfl_xor(l_run0, 16); l_run0 += __shfl_xor(l_run0, 32);
    l_run1 += __shfl_xor(l_run1, 16); l_run1 += __shfl_xor(l_run1, 32);

    // dump raw partials, coalesced: per (qs,dt) one 1KB wave-store of a
    // 16q x 16d tile in [q][d] order at f32 offset col*16 + g*4.
    float* op = O_part + (size_t)bid * 32768 + wave * 4096;
#pragma unroll
    for (int qs = 0; qs < 2; ++qs)
#pragma unroll
        for (int dt = 0; dt < 8; ++dt) {
            int j = qs * 8 + dt;
            *(f32x4*)(op + j * 256 + col * 16 + g * 4) = acc[qs][dt];
        }
    if (dh == 0 && g == 0) {
        lsum_part[bid * 128 + qq * 32 + col]      = l_run0;
        lsum_part[bid * 128 + qq * 32 + 16 + col] = l_run1;
    }
}

// ---------------------------------------------------------------------------
// Kernel 3: epilogue. out[b,s,k,d] = gamma * (sum_ks O_part)/(sum_ks l) + x.
// ---------------------------------------------------------------------------
__global__ __launch_bounds__(256) void epi_kernel(
    const float* __restrict__ O_part, const float* __restrict__ lsum_part,
    const float* __restrict__ x, const float* __restrict__ gamma_p,
    float* __restrict__ out)
{
    int gid = blockIdx.x * 256 + threadIdx.x;   // 0..524287
    int d  = (gid & 63) * 4;
    int nl = gid >> 6;
    int b  = nl >> 12;
    int n  = nl & (N_ - 1);

    int qt = n >> 7, qq = (n >> 5) & 3, qs = (n >> 4) & 1, col = n & 15;
    int dh = d >> 7, dt = (d >> 4) & 7;
    int w = qq * 2 + dh, j = qs * 8 + dt;
    int boff = w * 4096 + j * 256 + col * 16 + (d & 15);
    int loff = qq * 32 + qs * 16 + col;

    f32x4 acc = {0.f, 0.f, 0.f, 0.f};
    float l = 0.f;
#pragma unroll
    for (int ks = 0; ks < 4; ++ks) {
        int bid = qt * 8 + b * 4 + ks;
        f32x4 p = *(const f32x4*)(O_part + (size_t)bid * 32768 + boff);
        acc[0] += p[0]; acc[1] += p[1]; acc[2] += p[2]; acc[3] += p[3];
        l += lsum_part[bid * 128 + loff];
    }
    float scale = gamma_p[0] / l;
    int s = n & 63, kk = n >> 6;
    size_t o = (((size_t)(b * S_ + s)) * K_ + kk) * D_ + d;
    f32x4 xv = *(const f32x4*)(x + o);
    f32x4 ov;
#pragma unroll
    for (int e = 0; e < 4; ++e) ov[e] = acc[e] * scale + xv[e];
    *(f32x4*)(out + o) = ov;
}

extern "C" void kernel_launch(void* const* d_in, const int* in_sizes, int n_in,
                              void* d_out, int out_size, void* d_ws, size_t ws_size,
                              hipStream_t stream) {
    const float* x  = (const float*)d_in[0];
    const float* Wq = (const float*)d_in[1];
    const float* bq = (const float*)d_in[2];
    const float* Wk = (const float*)d_in[3];
    const float* bk = (const float*)d_in[4];
    const float* Wv = (const float*)d_in[5];
    const float* bv = (const float*)d_in[6];
    const float* gm = (const float*)d_in[7];

    char* ws = (char*)d_ws;
    unsigned short* Wh   = (unsigned short*)(ws);                 // 160KB
    unsigned short* Wl   = (unsigned short*)(ws + 0x40000);       // 160KB
    float*          bcat = (float*)         (ws + 0x80000);       // 1.3KB
    unsigned short* Qh   = (unsigned short*)(ws + 0x100000);      // 512KB
    unsigned short* Ql   = (unsigned short*)(ws + 0x180000);
    unsigned short* Kh   = (unsigned short*)(ws + 0x200000);
    unsigned short* Kl   = (unsigned short*)(ws + 0x280000);
    unsigned short* Vm   = (unsigned short*)(ws + 0x300000);      // 4MB
    float*          Op   = (float*)         (ws + 0x700000);      // 32MB
    float*          lp   = (float*)         (ws + 0x2700000);     // 128KB
    float* o = (float*)d_out;

    wcvt_kernel<<<320, 256, 0, stream>>>(Wq, bq, Wk, bk, Wv, bv, Wh, Wl, bcat);
    qkv_kernel<<<512, 256, 0, stream>>>(x, Wh, Wl, bcat, Qh, Ql, Kh, Kl, Vm);
    attn_kernel<<<256, 512, 0, stream>>>(Qh, Ql, Kh, Kl, Vm, Op, lp);
    epi_kernel<<<2048, 256, 0, stream>>>(Op, lp, x, gm, o);
}

// Round 16
// 77.011 us; speedup vs baseline: 5.2664x; 1.0918x over previous
//
#include <hip/hip_runtime.h>
#include <stdint.h>
#include <math.h>

using short8   = __attribute__((ext_vector_type(8))) short;
using ushort4v = __attribute__((ext_vector_type(4))) unsigned short;
using f32x4    = __attribute__((ext_vector_type(4))) float;
using uint4v   = __attribute__((ext_vector_type(4))) unsigned int;

#define B_ 2
#define S_ 64
#define K_ 64
#define D_ 256
#define C_ 32
#define N_ 4096  /* S_*K_ */
#define LOG2E 1.4426950408889634f

__device__ __forceinline__ float b2f(unsigned short u) {
    unsigned int v = ((unsigned int)u) << 16;
    return __builtin_bit_cast(float, v);
}
__device__ __forceinline__ unsigned short f2b(float f) {   // RNE f32->bf16
    unsigned int x = __builtin_bit_cast(unsigned int, f);
    x += 0x7fffu + ((x >> 16) & 1u);
    return (unsigned short)(x >> 16);
}
// pack two f32 -> bf16x2 (a low, b high), RNE, pure ALU (m240)
__device__ __forceinline__ unsigned int pk2(float a, float b) {
    unsigned int xa = __builtin_bit_cast(unsigned int, a);
    unsigned int xb = __builtin_bit_cast(unsigned int, b);
    xa += 0x7fffu + ((xa >> 16) & 1u);
    xb += 0x7fffu + ((xb >> 16) & 1u);
    return (xa >> 16) | (xb & 0xffff0000u);
}

// ---------------------------------------------------------------------------
// Kernel 0: W/bias pre-convert. oc 0-31 Q (x log2e), 32-63 K, 64-319 V.
// ---------------------------------------------------------------------------
__global__ __launch_bounds__(256) void wcvt_kernel(
    const float* __restrict__ Wq, const float* __restrict__ bq,
    const float* __restrict__ Wk, const float* __restrict__ bk,
    const float* __restrict__ Wv, const float* __restrict__ bv,
    unsigned short* __restrict__ Wh, unsigned short* __restrict__ Wl,
    float* __restrict__ bcat)
{
    int oc = blockIdx.x;            // 0..319
    int d  = threadIdx.x;           // 0..255
    float w;
    if (oc < 32)       w = Wq[oc * 256 + d] * LOG2E;
    else if (oc < 64)  w = Wk[(oc - 32) * 256 + d];
    else               w = Wv[(oc - 64) * 256 + d];
    unsigned short h = f2b(w);
    Wh[oc * 256 + d] = h;
    Wl[oc * 256 + d] = f2b(w - b2f(h));
    if (d == 0) {
        float bb;
        if (oc < 32)      bb = bq[oc] * LOG2E;
        else if (oc < 64) bb = bk[oc - 32];
        else              bb = bv[oc - 64];
        bcat[oc] = bb;
    }
}

// ---------------------------------------------------------------------------
// Kernel 1: QKV projections. Q,K [B][N][C] hi/lo. V chunk-interleaved
// [B][N/32][D*32] with (a) slot-permuted in-chunk token order
// (s = 8*((j&15)>>2) + ((j&16)>>2) + (j&3), matches attn's register-P) and
// (b) byte-level XOR swizzle o ^= (d&7)<<4 within the 16KB chunk, so attn's
// LINEAR LDS stage + swizzled ds_read is bank-balanced (both-sides rule).
// ---------------------------------------------------------------------------
__global__ __launch_bounds__(256) void qkv_kernel(
    const float* __restrict__ x,
    const unsigned short* __restrict__ Wh, const unsigned short* __restrict__ Wl,
    const float* __restrict__ bcat,
    unsigned short* __restrict__ Qh, unsigned short* __restrict__ Ql,
    unsigned short* __restrict__ Kh, unsigned short* __restrict__ Kl,
    unsigned short* __restrict__ Vm)
{
    __shared__ unsigned short lxh[16 * 256];   // [tok][d] bf16-hi, swizzled
    __shared__ unsigned short lxl[16 * 256];   // bf16-lo

    int tid = threadIdx.x;
    int bid = blockIdx.x;
    int b  = bid >> 8;
    int n0 = (bid & 255) << 4;

    {
        int tt = tid >> 4, dg0 = (tid & 15) * 16;
        int n = n0 + tt;
        int s = n & 63, kk = n >> 6;
        const float* xr = x + (((size_t)(b * S_ + s)) * K_ + kk) * D_ + dg0;
        short8 h0, l0, h1, l1;
#pragma unroll
        for (int e = 0; e < 8; ++e) {
            float v = xr[e];
            unsigned short hh = f2b(v);
            h0[e] = (short)hh; l0[e] = (short)f2b(v - b2f(hh));
        }
#pragma unroll
        for (int e = 0; e < 8; ++e) {
            float v = xr[8 + e];
            unsigned short hh = f2b(v);
            h1[e] = (short)hh; l1[e] = (short)f2b(v - b2f(hh));
        }
        int m0 = dg0 >> 3;
        int sw0 = ((m0 ^ (tt & 7)) << 3);
        int sw1 = (((m0 + 1) ^ (tt & 7)) << 3);
        *(short8*)(lxh + tt * 256 + sw0) = h0;
        *(short8*)(lxh + tt * 256 + sw1) = h1;
        *(short8*)(lxl + tt * 256 + sw0) = l0;
        *(short8*)(lxl + tt * 256 + sw1) = l1;
    }
    __syncthreads();

    int wave = tid >> 6, lane = tid & 63;
    int col = lane & 15, g = lane >> 4;

#pragma unroll
    for (int i = 0; i < 5; ++i) {
        int ct = wave + i * 4;                   // 0..19
        int oc0 = ct * 16;
        const unsigned short* whr = Wh + (size_t)(oc0 + col) * 256;
        const unsigned short* wlr = Wl + (size_t)(oc0 + col) * 256;
        f32x4 acc = {0.f, 0.f, 0.f, 0.f};

        if (ct < 4) {                            // Q/K: split-bf16 3-chain
#pragma unroll
            for (int dc = 0; dc < 8; ++dc) {
                int sw = (((dc * 4 + g) ^ (col & 7)) << 3);
                short8 xh8 = *(const short8*)(lxh + col * 256 + sw);
                short8 xl8 = *(const short8*)(lxl + col * 256 + sw);
                short8 wh8 = *(const short8*)(whr + dc * 32 + g * 8);
                short8 wl8 = *(const short8*)(wlr + dc * 32 + g * 8);
                acc = __builtin_amdgcn_mfma_f32_16x16x32_bf16(xl8, wh8, acc, 0, 0, 0);
                acc = __builtin_amdgcn_mfma_f32_16x16x32_bf16(xh8, wl8, acc, 0, 0, 0);
                acc = __builtin_amdgcn_mfma_f32_16x16x32_bf16(xh8, wh8, acc, 0, 0, 0);
            }
            float bb = bcat[oc0 + col];
            unsigned short* Th = (ct < 2) ? Qh : Kh;
            unsigned short* Tl = (ct < 2) ? Ql : Kl;
            int c0 = (ct & 1) * 16;
#pragma unroll
            for (int r = 0; r < 4; ++r) {
                int tok = n0 + g * 4 + r;
                float v = acc[r] + bb;
                unsigned short hh = f2b(v);
                size_t idx = ((size_t)b * N_ + tok) * C_ + c0 + col;
                Th[idx] = hh;
                Tl[idx] = f2b(v - b2f(hh));
            }
        } else {                                 // V: single bf16
#pragma unroll
            for (int dc = 0; dc < 8; ++dc) {
                int sw = (((dc * 4 + g) ^ (col & 7)) << 3);
                short8 xh8 = *(const short8*)(lxh + col * 256 + sw);
                short8 wh8 = *(const short8*)(whr + dc * 32 + g * 8);
                acc = __builtin_amdgcn_mfma_f32_16x16x32_bf16(xh8, wh8, acc, 0, 0, 0);
            }
            float bb = bcat[oc0 + col];
            int c0 = oc0 - 64;
            ushort4v st;
#pragma unroll
            for (int r = 0; r < 4; ++r) st[r] = f2b(acc[r] + bb);
            int tok0 = n0 + g * 4;
            int s0 = 8 * g + ((n0 & 16) >> 2);   // slot-permuted in-chunk pos
            int d_ch = c0 + col;
            int o = d_ch * 64 + s0 * 2;          // byte offset within 16KB chunk
            o ^= (d_ch & 7) << 4;                // bank-swizzle (8B-run safe)
            size_t vbyteoff = ((size_t)b * (N_ / 32) + (tok0 >> 5)) * (D_ * 32 * 2)
                            + (size_t)o;
            *(ushort4v*)((char*)Vm + vbyteoff) = st;
        }
    }
}

// ---------------------------------------------------------------------------
// Kernel 2: flash attention with V-through-LDS dedup. R15 structure (256
// blocks = 2b x 4ks x 32qt; 8 waves = 4qq x 2dh; wave = 32q x 128d x 1024
// keys), but V is staged ONCE per block per iteration into LDS (16KB chunk,
// double-buffered) instead of each wave loading it: L1 traffic 96->48 KB
// per CU-iter (V was read 4x redundantly through L1; L1 doesn't broadcast
// across waves). T14 split: stage loads issued at phase top, ds_write after
// PV, one __syncthreads per iteration. ds_reads use the source-side XOR
// swizzle (o ^ (col&7)<<4) for bank balance. K keeps the verified A/B
// register prefetch. Register-only P (slot-permuted V), exp2 softmax.
// ---------------------------------------------------------------------------
__global__ __launch_bounds__(512, 2) void attn_kernel(
    const unsigned short* __restrict__ Qh, const unsigned short* __restrict__ Ql,
    const unsigned short* __restrict__ Kh, const unsigned short* __restrict__ Kl,
    const unsigned short* __restrict__ Vm,
    float* __restrict__ O_part, float* __restrict__ lsum_part)
{
    __shared__ __align__(16) char vlds[2][16384];   // V chunk double-buffer

    int tid  = threadIdx.x;
    int wave = tid >> 6;
    int lane = tid & 63;
    int col = lane & 15, g = lane >> 4;
    int qq = wave >> 1;           // q-quarter 0..3
    int dh = wave & 1;            // d-half 0..1
    int dbase = dh * 128;

    int bid = blockIdx.x;
    int x7 = bid & 7;
    int b  = x7 >> 2;
    int ks = x7 & 3;
    int qt = bid >> 3;            // 0..31 (q-tile within batch)
    int q0 = qt * 128 + qq * 32;
    int jbase = ks * (N_ / 4);

    size_t qoff0 = ((size_t)b * N_ + q0 + col) * C_ + g * 8;
    size_t qoff1 = ((size_t)b * N_ + q0 + 16 + col) * C_ + g * 8;
    short8 qfh0 = *(const short8*)(Qh + qoff0);
    short8 qfl0 = *(const short8*)(Ql + qoff0);
    short8 qfh1 = *(const short8*)(Qh + qoff1);
    short8 qfl1 = *(const short8*)(Ql + qoff1);

    f32x4 acc[2][8];
#pragma unroll
    for (int qs = 0; qs < 2; ++qs)
#pragma unroll
        for (int dt = 0; dt < 8; ++dt) acc[qs][dt] = (f32x4){0.f, 0.f, 0.f, 0.f};
    float l_run0 = 0.f, l_run1 = 0.f;

    const unsigned short* kbh = Kh + (size_t)b * N_ * C_;
    const unsigned short* kbl = Kl + (size_t)b * N_ * C_;
    const char* vbyte = (const char*)Vm + (size_t)b * ((size_t)N_ * D_ * 2);

    auto kaddr0 = [&](int it) { return (size_t)(jbase + it * 32 + col) * C_ + g * 8; };
    auto kaddr1 = [&](int it) { return (size_t)(jbase + it * 32 + 16 + col) * C_ + g * 8; };

    // lane-constant swizzled ds_read offset: logical (dbase+dt*16+col)*64+g*16,
    // phys ^= (col&7)<<4 (matches qkv's source swizzle; +dt*1024 is additive)
    unsigned vro = (unsigned)(((dbase + col) * 64 + g * 16) ^ ((col & 7) << 4));

    // prologue: stage chunk(it=0) into vlds[0]; K(0) into the A set
    {
        const char* vsrc = vbyte + (size_t)(ks * 32) * 16384 + tid * 16;
        f32x4 s0 = *(const f32x4*)(vsrc);
        f32x4 s1 = *(const f32x4*)(vsrc + 8192);
        *(f32x4*)(vlds[0] + tid * 16)        = s0;
        *(f32x4*)(vlds[0] + tid * 16 + 8192) = s1;
    }
    short8 kh0A = *(const short8*)(kbh + kaddr0(0));
    short8 kl0A = *(const short8*)(kbl + kaddr0(0));
    short8 kh1A = *(const short8*)(kbh + kaddr1(0));
    short8 kl1A = *(const short8*)(kbl + kaddr1(0));
    short8 kh0B, kl0B, kh1B, kl1B;
    __syncthreads();

    // one phase: stage V(IT+1) (issue early / ds_write late), K prefetch,
    // QK+softmax on CUR K set, PV from vlds[RB], barrier. IT+1 may be one
    // past the end: reads land in adjacent ws regions, staged then unused.
#define ATTN_PHASE(IT, RB, WB, CKH0, CKL0, CKH1, CKL1, NKH0, NKL0, NKH1, NKL1)   \
    {                                                                            \
        int itn_ = (IT) + 1;                                                     \
        const char* vsrc_ = vbyte + (size_t)(ks * 32 + itn_) * 16384 + tid * 16; \
        f32x4 stg0_ = *(const f32x4*)(vsrc_);                                    \
        f32x4 stg1_ = *(const f32x4*)(vsrc_ + 8192);                             \
        NKH0 = *(const short8*)(kbh + kaddr0(itn_));                             \
        NKL0 = *(const short8*)(kbl + kaddr0(itn_));                             \
        NKH1 = *(const short8*)(kbh + kaddr1(itn_));                             \
        NKL1 = *(const short8*)(kbl + kaddr1(itn_));                             \
        __builtin_amdgcn_sched_barrier(0);  /* loads stay issued up here */      \
        f32x4 z_ = {0.f, 0.f, 0.f, 0.f};                                         \
        f32x4 s00 = __builtin_amdgcn_mfma_f32_16x16x32_bf16(CKL0, qfh0, z_, 0, 0, 0); \
        s00 = __builtin_amdgcn_mfma_f32_16x16x32_bf16(CKH0, qfl0, s00, 0, 0, 0); \
        s00 = __builtin_amdgcn_mfma_f32_16x16x32_bf16(CKH0, qfh0, s00, 0, 0, 0); \
        f32x4 s01 = __builtin_amdgcn_mfma_f32_16x16x32_bf16(CKL1, qfh0, z_, 0, 0, 0); \
        s01 = __builtin_amdgcn_mfma_f32_16x16x32_bf16(CKH1, qfl0, s01, 0, 0, 0); \
        s01 = __builtin_amdgcn_mfma_f32_16x16x32_bf16(CKH1, qfh0, s01, 0, 0, 0); \
        f32x4 s10 = __builtin_amdgcn_mfma_f32_16x16x32_bf16(CKL0, qfh1, z_, 0, 0, 0); \
        s10 = __builtin_amdgcn_mfma_f32_16x16x32_bf16(CKH0, qfl1, s10, 0, 0, 0); \
        s10 = __builtin_amdgcn_mfma_f32_16x16x32_bf16(CKH0, qfh1, s10, 0, 0, 0); \
        f32x4 s11 = __builtin_amdgcn_mfma_f32_16x16x32_bf16(CKL1, qfh1, z_, 0, 0, 0); \
        s11 = __builtin_amdgcn_mfma_f32_16x16x32_bf16(CKH1, qfl1, s11, 0, 0, 0); \
        s11 = __builtin_amdgcn_mfma_f32_16x16x32_bf16(CKH1, qfh1, s11, 0, 0, 0); \
        float pa[4], pc[4], pe[4], pg[4];                                        \
        _Pragma("unroll")                                                        \
        for (int r = 0; r < 4; ++r) {                                            \
            pa[r] = exp2f(s00[r]);                                               \
            pc[r] = exp2f(s01[r]);                                               \
            pe[r] = exp2f(s10[r]);                                               \
            pg[r] = exp2f(s11[r]);                                               \
        }                                                                        \
        l_run0 += (pa[0] + pa[1]) + (pa[2] + pa[3])                              \
                + (pc[0] + pc[1]) + (pc[2] + pc[3]);                             \
        l_run1 += (pe[0] + pe[1]) + (pe[2] + pe[3])                              \
                + (pg[0] + pg[1]) + (pg[2] + pg[3]);                             \
        uint4v u0, u1;                                                           \
        u0[0] = pk2(pa[0], pa[1]); u0[1] = pk2(pa[2], pa[3]);                    \
        u0[2] = pk2(pc[0], pc[1]); u0[3] = pk2(pc[2], pc[3]);                    \
        u1[0] = pk2(pe[0], pe[1]); u1[1] = pk2(pe[2], pe[3]);                    \
        u1[2] = pk2(pg[0], pg[1]); u1[3] = pk2(pg[2], pg[3]);                    \
        short8 pf0 = __builtin_bit_cast(short8, u0);                             \
        short8 pf1 = __builtin_bit_cast(short8, u1);                             \
        short8 vf_[8];                                                           \
        _Pragma("unroll")                                                        \
        for (int dt = 0; dt < 8; ++dt)                                           \
            vf_[dt] = *(const short8*)(vlds[RB] + vro + dt * 1024);              \
        _Pragma("unroll")                                                        \
        for (int dt = 0; dt < 8; ++dt) {                                         \
            acc[0][dt] = __builtin_amdgcn_mfma_f32_16x16x32_bf16(vf_[dt], pf0, acc[0][dt], 0, 0, 0); \
            acc[1][dt] = __builtin_amdgcn_mfma_f32_16x16x32_bf16(vf_[dt], pf1, acc[1][dt], 0, 0, 0); \
        }                                                                        \
        *(f32x4*)(vlds[WB] + tid * 16)        = stg0_;                           \
        *(f32x4*)(vlds[WB] + tid * 16 + 8192) = stg1_;                           \
        __syncthreads();                                                         \
    }

    for (int it2 = 0; it2 < 16; ++it2) {
        int itA = it2 * 2, itB = itA + 1;
        ATTN_PHASE(itA, 0, 1, kh0A, kl0A, kh1A, kl1A, kh0B, kl0B, kh1B, kl1B);
        ATTN_PHASE(itB, 1, 0, kh0B, kl0B, kh1B, kl1B, kh0A, kl0A, kh1A, kl1A);
    }
#undef ATTN_PHASE

    // final l reduction across the 4 g-groups
    l_run0 += __shfl_xor(l_run0, 16); l_run0 += __shfl_xor(l_run0, 32);
    l_run1 += __shfl_xor(l_run1, 16); l_run1 += __shfl_xor(l_run1, 32);

    // dump raw partials, coalesced: per (qs,dt) one 1KB wave-store of a
    // 16q x 16d tile in [q][d] order at f32 offset col*16 + g*4.
    float* op = O_part + (size_t)bid * 32768 + wave * 4096;
#pragma unroll
    for (int qs = 0; qs < 2; ++qs)
#pragma unroll
        for (int dt = 0; dt < 8; ++dt) {
            int j = qs * 8 + dt;
            *(f32x4*)(op + j * 256 + col * 16 + g * 4) = acc[qs][dt];
        }
    if (dh == 0 && g == 0) {
        lsum_part[bid * 128 + qq * 32 + col]      = l_run0;
        lsum_part[bid * 128 + qq * 32 + 16 + col] = l_run1;
    }
}

// ---------------------------------------------------------------------------
// Kernel 3: epilogue. out[b,s,k,d] = gamma * (sum_ks O_part)/(sum_ks l) + x.
// ---------------------------------------------------------------------------
__global__ __launch_bounds__(256) void epi_kernel(
    const float* __restrict__ O_part, const float* __restrict__ lsum_part,
    const float* __restrict__ x, const float* __restrict__ gamma_p,
    float* __restrict__ out)
{
    int gid = blockIdx.x * 256 + threadIdx.x;   // 0..524287
    int d  = (gid & 63) * 4;
    int nl = gid >> 6;
    int b  = nl >> 12;
    int n  = nl & (N_ - 1);

    int qt = n >> 7, qq = (n >> 5) & 3, qs = (n >> 4) & 1, col = n & 15;
    int dh = d >> 7, dt = (d >> 4) & 7;
    int w = qq * 2 + dh, j = qs * 8 + dt;
    int boff = w * 4096 + j * 256 + col * 16 + (d & 15);
    int loff = qq * 32 + qs * 16 + col;

    f32x4 acc = {0.f, 0.f, 0.f, 0.f};
    float l = 0.f;
#pragma unroll
    for (int ks = 0; ks < 4; ++ks) {
        int bid = qt * 8 + b * 4 + ks;
        f32x4 p = *(const f32x4*)(O_part + (size_t)bid * 32768 + boff);
        acc[0] += p[0]; acc[1] += p[1]; acc[2] += p[2]; acc[3] += p[3];
        l += lsum_part[bid * 128 + loff];
    }
    float scale = gamma_p[0] / l;
    int s = n & 63, kk = n >> 6;
    size_t o = (((size_t)(b * S_ + s)) * K_ + kk) * D_ + d;
    f32x4 xv = *(const f32x4*)(x + o);
    f32x4 ov;
#pragma unroll
    for (int e = 0; e < 4; ++e) ov[e] = acc[e] * scale + xv[e];
    *(f32x4*)(out + o) = ov;
}

extern "C" void kernel_launch(void* const* d_in, const int* in_sizes, int n_in,
                              void* d_out, int out_size, void* d_ws, size_t ws_size,
                              hipStream_t stream) {
    const float* x  = (const float*)d_in[0];
    const float* Wq = (const float*)d_in[1];
    const float* bq = (const float*)d_in[2];
    const float* Wk = (const float*)d_in[3];
    const float* bk = (const float*)d_in[4];
    const float* Wv = (const float*)d_in[5];
    const float* bv = (const float*)d_in[6];
    const float* gm = (const float*)d_in[7];

    char* ws = (char*)d_ws;
    unsigned short* Wh   = (unsigned short*)(ws);                 // 160KB
    unsigned short* Wl   = (unsigned short*)(ws + 0x40000);       // 160KB
    float*          bcat = (float*)         (ws + 0x80000);       // 1.3KB
    unsigned short* Qh   = (unsigned short*)(ws + 0x100000);      // 512KB
    unsigned short* Ql   = (unsigned short*)(ws + 0x180000);
    unsigned short* Kh   = (unsigned short*)(ws + 0x200000);
    unsigned short* Kl   = (unsigned short*)(ws + 0x280000);
    unsigned short* Vm   = (unsigned short*)(ws + 0x300000);      // 4MB
    float*          Op   = (float*)         (ws + 0x700000);      // 32MB
    float*          lp   = (float*)         (ws + 0x2700000);     // 128KB
    float* o = (float*)d_out;

    wcvt_kernel<<<320, 256, 0, stream>>>(Wq, bq, Wk, bk, Wv, bv, Wh, Wl, bcat);
    qkv_kernel<<<512, 256, 0, stream>>>(x, Wh, Wl, bcat, Qh, Ql, Kh, Kl, Vm);
    attn_kernel<<<256, 512, 0, stream>>>(Qh, Ql, Kh, Kl, Vm, Op, lp);
    epi_kernel<<<2048, 256, 0, stream>>>(Op, lp, x, gm, o);
}

// Round 17
// 69.438 us; speedup vs baseline: 5.8407x; 1.1091x over previous
//
#include <hip/hip_runtime.h>
#include <stdint.h>
#include <math.h>

using short8   = __attribute__((ext_vector_type(8))) short;
using ushort4v = __attribute__((ext_vector_type(4))) unsigned short;
using f32x4    = __attribute__((ext_vector_type(4))) float;
using uint4v   = __attribute__((ext_vector_type(4))) unsigned int;

#define B_ 2
#define S_ 64
#define K_ 64
#define D_ 256
#define C_ 32
#define N_ 4096  /* S_*K_ */
#define LOG2E 1.4426950408889634f

__device__ __forceinline__ float b2f(unsigned short u) {
    unsigned int v = ((unsigned int)u) << 16;
    return __builtin_bit_cast(float, v);
}
__device__ __forceinline__ unsigned short f2b(float f) {   // RNE f32->bf16
    unsigned int x = __builtin_bit_cast(unsigned int, f);
    x += 0x7fffu + ((x >> 16) & 1u);
    return (unsigned short)(x >> 16);
}
// pack two f32 -> bf16x2 (a low, b high), RNE, pure ALU (m240)
__device__ __forceinline__ unsigned int pk2(float a, float b) {
    unsigned int xa = __builtin_bit_cast(unsigned int, a);
    unsigned int xb = __builtin_bit_cast(unsigned int, b);
    xa += 0x7fffu + ((xa >> 16) & 1u);
    xb += 0x7fffu + ((xb >> 16) & 1u);
    return (xa >> 16) | (xb & 0xffff0000u);
}

// ---------------------------------------------------------------------------
// Kernel 0: W/bias pre-convert. oc 0-31 Q (x log2e), 32-63 K, 64-319 V.
// ---------------------------------------------------------------------------
__global__ __launch_bounds__(256) void wcvt_kernel(
    const float* __restrict__ Wq, const float* __restrict__ bq,
    const float* __restrict__ Wk, const float* __restrict__ bk,
    const float* __restrict__ Wv, const float* __restrict__ bv,
    unsigned short* __restrict__ Wh, unsigned short* __restrict__ Wl,
    float* __restrict__ bcat)
{
    int oc = blockIdx.x;            // 0..319
    int d  = threadIdx.x;           // 0..255
    float w;
    if (oc < 32)       w = Wq[oc * 256 + d] * LOG2E;
    else if (oc < 64)  w = Wk[(oc - 32) * 256 + d];
    else               w = Wv[(oc - 64) * 256 + d];
    unsigned short h = f2b(w);
    Wh[oc * 256 + d] = h;
    Wl[oc * 256 + d] = f2b(w - b2f(h));
    if (d == 0) {
        float bb;
        if (oc < 32)      bb = bq[oc] * LOG2E;
        else if (oc < 64) bb = bk[oc - 32];
        else              bb = bv[oc - 64];
        bcat[oc] = bb;
    }
}

// ---------------------------------------------------------------------------
// Kernel 1: QKV projections (verified). Q,K [B][N][C] hi/lo. V chunk-
// interleaved [B][N/32][D*32]: slot-permuted in-chunk token order
// (s = 8*((j&15)>>2) + ((j&16)>>2) + (j&3)) + byte XOR swizzle
// o ^= (d&7)<<4 within the 16KB chunk (bank-balance for attn's LDS path).
// ---------------------------------------------------------------------------
__global__ __launch_bounds__(256) void qkv_kernel(
    const float* __restrict__ x,
    const unsigned short* __restrict__ Wh, const unsigned short* __restrict__ Wl,
    const float* __restrict__ bcat,
    unsigned short* __restrict__ Qh, unsigned short* __restrict__ Ql,
    unsigned short* __restrict__ Kh, unsigned short* __restrict__ Kl,
    unsigned short* __restrict__ Vm)
{
    __shared__ unsigned short lxh[16 * 256];   // [tok][d] bf16-hi, swizzled
    __shared__ unsigned short lxl[16 * 256];   // bf16-lo

    int tid = threadIdx.x;
    int bid = blockIdx.x;
    int b  = bid >> 8;
    int n0 = (bid & 255) << 4;

    {
        int tt = tid >> 4, dg0 = (tid & 15) * 16;
        int n = n0 + tt;
        int s = n & 63, kk = n >> 6;
        const float* xr = x + (((size_t)(b * S_ + s)) * K_ + kk) * D_ + dg0;
        short8 h0, l0, h1, l1;
#pragma unroll
        for (int e = 0; e < 8; ++e) {
            float v = xr[e];
            unsigned short hh = f2b(v);
            h0[e] = (short)hh; l0[e] = (short)f2b(v - b2f(hh));
        }
#pragma unroll
        for (int e = 0; e < 8; ++e) {
            float v = xr[8 + e];
            unsigned short hh = f2b(v);
            h1[e] = (short)hh; l1[e] = (short)f2b(v - b2f(hh));
        }
        int m0 = dg0 >> 3;
        int sw0 = ((m0 ^ (tt & 7)) << 3);
        int sw1 = (((m0 + 1) ^ (tt & 7)) << 3);
        *(short8*)(lxh + tt * 256 + sw0) = h0;
        *(short8*)(lxh + tt * 256 + sw1) = h1;
        *(short8*)(lxl + tt * 256 + sw0) = l0;
        *(short8*)(lxl + tt * 256 + sw1) = l1;
    }
    __syncthreads();

    int wave = tid >> 6, lane = tid & 63;
    int col = lane & 15, g = lane >> 4;

#pragma unroll
    for (int i = 0; i < 5; ++i) {
        int ct = wave + i * 4;                   // 0..19
        int oc0 = ct * 16;
        const unsigned short* whr = Wh + (size_t)(oc0 + col) * 256;
        const unsigned short* wlr = Wl + (size_t)(oc0 + col) * 256;
        f32x4 acc = {0.f, 0.f, 0.f, 0.f};

        if (ct < 4) {                            // Q/K: split-bf16 3-chain
#pragma unroll
            for (int dc = 0; dc < 8; ++dc) {
                int sw = (((dc * 4 + g) ^ (col & 7)) << 3);
                short8 xh8 = *(const short8*)(lxh + col * 256 + sw);
                short8 xl8 = *(const short8*)(lxl + col * 256 + sw);
                short8 wh8 = *(const short8*)(whr + dc * 32 + g * 8);
                short8 wl8 = *(const short8*)(wlr + dc * 32 + g * 8);
                acc = __builtin_amdgcn_mfma_f32_16x16x32_bf16(xl8, wh8, acc, 0, 0, 0);
                acc = __builtin_amdgcn_mfma_f32_16x16x32_bf16(xh8, wl8, acc, 0, 0, 0);
                acc = __builtin_amdgcn_mfma_f32_16x16x32_bf16(xh8, wh8, acc, 0, 0, 0);
            }
            float bb = bcat[oc0 + col];
            unsigned short* Th = (ct < 2) ? Qh : Kh;
            unsigned short* Tl = (ct < 2) ? Ql : Kl;
            int c0 = (ct & 1) * 16;
#pragma unroll
            for (int r = 0; r < 4; ++r) {
                int tok = n0 + g * 4 + r;
                float v = acc[r] + bb;
                unsigned short hh = f2b(v);
                size_t idx = ((size_t)b * N_ + tok) * C_ + c0 + col;
                Th[idx] = hh;
                Tl[idx] = f2b(v - b2f(hh));
            }
        } else {                                 // V: single bf16
#pragma unroll
            for (int dc = 0; dc < 8; ++dc) {
                int sw = (((dc * 4 + g) ^ (col & 7)) << 3);
                short8 xh8 = *(const short8*)(lxh + col * 256 + sw);
                short8 wh8 = *(const short8*)(whr + dc * 32 + g * 8);
                acc = __builtin_amdgcn_mfma_f32_16x16x32_bf16(xh8, wh8, acc, 0, 0, 0);
            }
            float bb = bcat[oc0 + col];
            int c0 = oc0 - 64;
            ushort4v st;
#pragma unroll
            for (int r = 0; r < 4; ++r) st[r] = f2b(acc[r] + bb);
            int tok0 = n0 + g * 4;
            int s0 = 8 * g + ((n0 & 16) >> 2);   // slot-permuted in-chunk pos
            int d_ch = c0 + col;
            int o = d_ch * 64 + s0 * 2;          // byte offset within 16KB chunk
            o ^= (d_ch & 7) << 4;                // bank-swizzle (8B-run safe)
            size_t vbyteoff = ((size_t)b * (N_ / 32) + (tok0 >> 5)) * (D_ * 32 * 2)
                            + (size_t)o;
            *(ushort4v*)((char*)Vm + vbyteoff) = st;
        }
    }
}

// ---------------------------------------------------------------------------
// Kernel 2: flash attention, V-through-LDS (R16 verified) + SKEWED TWIN
// P-EXCHANGE: waves (qq,0)/(qq,1) previously duplicated QK+softmax; now
// twin dh computes ONLY its q-subtile's scores for iteration it+1 during
// phase it (6 MFMA, 8 exp2, 4 pk2 — half), publishes its 16B/lane P-frag
// to double-buffered LDS before the (already existing) per-phase barrier;
// PV(it) reads both halves via ds_read_b128 (lane-linear, conflict-free).
// K prefetch distance 2 (A/B sets, wrap-free). Peeled: prologue QK(0),
// 31 phases [QK(it+1) + PV(it)], epilogue PV(31). Each wave owns its
// lsum slot (plain store). Everything else as R16.
// ---------------------------------------------------------------------------
__global__ __launch_bounds__(512, 2) void attn_kernel(
    const unsigned short* __restrict__ Qh, const unsigned short* __restrict__ Ql,
    const unsigned short* __restrict__ Kh, const unsigned short* __restrict__ Kl,
    const unsigned short* __restrict__ Vm,
    float* __restrict__ O_part, float* __restrict__ lsum_part)
{
    __shared__ __align__(16) char vlds[2][16384];   // V chunk double-buffer
    __shared__ __align__(16) char plds[2 * 8192];   // P exchange double-buffer

    int tid  = threadIdx.x;
    int wave = tid >> 6;
    int lane = tid & 63;
    int col = lane & 15, g = lane >> 4;
    int qq = wave >> 1;           // q-quarter 0..3
    int dh = wave & 1;            // own q-subtile (and d-half for PV)
    int dbase = dh * 128;
    int tid16 = tid * 16;
    int lane16 = lane * 16;

    int bid = blockIdx.x;
    int x7 = bid & 7;
    int b  = x7 >> 2;
    int ks = x7 & 3;
    int qt = bid >> 3;            // 0..31 (q-tile within batch)
    int q0 = qt * 128 + qq * 32;
    int jbase = ks * (N_ / 4);

    // Q fragments for OWN q-subtile only
    size_t qoff = ((size_t)b * N_ + q0 + dh * 16 + col) * C_ + g * 8;
    short8 qfh = *(const short8*)(Qh + qoff);
    short8 qfl = *(const short8*)(Ql + qoff);

    f32x4 acc[2][8];
#pragma unroll
    for (int qs = 0; qs < 2; ++qs)
#pragma unroll
        for (int dt = 0; dt < 8; ++dt) acc[qs][dt] = (f32x4){0.f, 0.f, 0.f, 0.f};
    float l_run = 0.f;

    const unsigned short* kbh = Kh + (size_t)b * N_ * C_;
    const unsigned short* kbl = Kl + (size_t)b * N_ * C_;
    const char* vbyte = (const char*)Vm + (size_t)b * ((size_t)N_ * D_ * 2);

    auto kaddr0 = [&](int it) { return (size_t)(jbase + it * 32 + col) * C_ + g * 8; };
    auto kaddr1 = [&](int it) { return (size_t)(jbase + it * 32 + 16 + col) * C_ + g * 8; };

    // lane-constant swizzled ds_read offset for V fragments
    unsigned vro = (unsigned)(((dbase + col) * 64 + g * 16) ^ ((col & 7) << 4));
    char* pmy = plds + qq * 2048 + dh * 1024 + lane16;   // own P write slot
    const char* pr0 = plds + qq * 2048 + lane16;          // qsub0 read
    const char* pr1 = plds + qq * 2048 + 1024 + lane16;   // qsub1 read

    // ---- prologue: stage V(0); K(0)->A, K(1)->B; QK(0) -> plds[0] ----
    {
        const char* vsrc = vbyte + (size_t)(ks * 32) * 16384 + tid16;
        f32x4 s0 = *(const f32x4*)(vsrc);
        f32x4 s1 = *(const f32x4*)(vsrc + 8192);
        *(f32x4*)(vlds[0] + tid16)        = s0;
        *(f32x4*)(vlds[0] + tid16 + 8192) = s1;
    }
    short8 kh0A = *(const short8*)(kbh + kaddr0(0));
    short8 kl0A = *(const short8*)(kbl + kaddr0(0));
    short8 kh1A = *(const short8*)(kbh + kaddr1(0));
    short8 kl1A = *(const short8*)(kbl + kaddr1(0));
    short8 kh0B = *(const short8*)(kbh + kaddr0(1));
    short8 kl0B = *(const short8*)(kbl + kaddr0(1));
    short8 kh1B = *(const short8*)(kbh + kaddr1(1));
    short8 kl1B = *(const short8*)(kbl + kaddr1(1));
    {
        f32x4 z = {0.f, 0.f, 0.f, 0.f};
        f32x4 sa = __builtin_amdgcn_mfma_f32_16x16x32_bf16(kl0A, qfh, z, 0, 0, 0);
        sa = __builtin_amdgcn_mfma_f32_16x16x32_bf16(kh0A, qfl, sa, 0, 0, 0);
        sa = __builtin_amdgcn_mfma_f32_16x16x32_bf16(kh0A, qfh, sa, 0, 0, 0);
        f32x4 sb = __builtin_amdgcn_mfma_f32_16x16x32_bf16(kl1A, qfh, z, 0, 0, 0);
        sb = __builtin_amdgcn_mfma_f32_16x16x32_bf16(kh1A, qfl, sb, 0, 0, 0);
        sb = __builtin_amdgcn_mfma_f32_16x16x32_bf16(kh1A, qfh, sb, 0, 0, 0);
        float pa[4], pb[4];
#pragma unroll
        for (int r = 0; r < 4; ++r) { pa[r] = exp2f(sa[r]); pb[r] = exp2f(sb[r]); }
        l_run += (pa[0] + pa[1]) + (pa[2] + pa[3]) + (pb[0] + pb[1]) + (pb[2] + pb[3]);
        uint4v uo;
        uo[0] = pk2(pa[0], pa[1]); uo[1] = pk2(pa[2], pa[3]);
        uo[2] = pk2(pb[0], pb[1]); uo[3] = pk2(pb[2], pb[3]);
        *(uint4v*)(pmy) = uo;   // buffer 0
    }
    __syncthreads();

    // phase IT: stage V(IT+1), prefetch K(IT+2), QK(IT+1) own-half (CUR set),
    // PV(IT) from plds/vlds[IT&1], publish P(IT+1)+V(IT+1), barrier.
#define ATTN_PHASE(IT, CKH0, CKL0, CKH1, CKL1, NKH0, NKL0, NKH1, NKL1)           \
    {                                                                            \
        int itn_ = (IT) + 1;                                                     \
        int itk_ = (IT) + 2;  /* may run past end: wrap-free, discarded */       \
        const char* vsrc_ = vbyte + (size_t)(ks * 32 + itn_) * 16384 + tid16;    \
        f32x4 stg0_ = *(const f32x4*)(vsrc_);                                    \
        f32x4 stg1_ = *(const f32x4*)(vsrc_ + 8192);                             \
        NKH0 = *(const short8*)(kbh + kaddr0(itk_));                             \
        NKL0 = *(const short8*)(kbl + kaddr0(itk_));                             \
        NKH1 = *(const short8*)(kbh + kaddr1(itk_));                             \
        NKL1 = *(const short8*)(kbl + kaddr1(itk_));                             \
        __builtin_amdgcn_sched_barrier(0);  /* loads stay issued up here */      \
        f32x4 z_ = {0.f, 0.f, 0.f, 0.f};                                         \
        f32x4 sa_ = __builtin_amdgcn_mfma_f32_16x16x32_bf16(CKL0, qfh, z_, 0, 0, 0); \
        sa_ = __builtin_amdgcn_mfma_f32_16x16x32_bf16(CKH0, qfl, sa_, 0, 0, 0);  \
        sa_ = __builtin_amdgcn_mfma_f32_16x16x32_bf16(CKH0, qfh, sa_, 0, 0, 0);  \
        f32x4 sb_ = __builtin_amdgcn_mfma_f32_16x16x32_bf16(CKL1, qfh, z_, 0, 0, 0); \
        sb_ = __builtin_amdgcn_mfma_f32_16x16x32_bf16(CKH1, qfl, sb_, 0, 0, 0);  \
        sb_ = __builtin_amdgcn_mfma_f32_16x16x32_bf16(CKH1, qfh, sb_, 0, 0, 0);  \
        float pa_[4], pb_[4];                                                    \
        _Pragma("unroll")                                                        \
        for (int r = 0; r < 4; ++r) { pa_[r] = exp2f(sa_[r]); pb_[r] = exp2f(sb_[r]); } \
        l_run += (pa_[0] + pa_[1]) + (pa_[2] + pa_[3])                           \
               + (pb_[0] + pb_[1]) + (pb_[2] + pb_[3]);                          \
        uint4v uo_;                                                              \
        uo_[0] = pk2(pa_[0], pa_[1]); uo_[1] = pk2(pa_[2], pa_[3]);              \
        uo_[2] = pk2(pb_[0], pb_[1]); uo_[3] = pk2(pb_[2], pb_[3]);              \
        int rb_ = (IT) & 1, wb_ = (itn_) & 1;                                    \
        short8 pf0_ = *(const short8*)(pr0 + rb_ * 8192);                        \
        short8 pf1_ = *(const short8*)(pr1 + rb_ * 8192);                        \
        short8 vf_[8];                                                           \
        _Pragma("unroll")                                                        \
        for (int dt = 0; dt < 8; ++dt)                                           \
            vf_[dt] = *(const short8*)(vlds[rb_] + vro + dt * 1024);             \
        _Pragma("unroll")                                                        \
        for (int dt = 0; dt < 8; ++dt) {                                         \
            acc[0][dt] = __builtin_amdgcn_mfma_f32_16x16x32_bf16(vf_[dt], pf0_, acc[0][dt], 0, 0, 0); \
            acc[1][dt] = __builtin_amdgcn_mfma_f32_16x16x32_bf16(vf_[dt], pf1_, acc[1][dt], 0, 0, 0); \
        }                                                                        \
        *(uint4v*)(pmy + wb_ * 8192) = uo_;                                      \
        *(f32x4*)(vlds[wb_] + tid16)        = stg0_;                             \
        *(f32x4*)(vlds[wb_] + tid16 + 8192) = stg1_;                             \
        __syncthreads();                                                         \
    }

    for (int it2 = 0; it2 < 15; ++it2) {
        int itA = it2 * 2, itB = itA + 1;
        ATTN_PHASE(itA, kh0B, kl0B, kh1B, kl1B, kh0A, kl0A, kh1A, kl1A);
        ATTN_PHASE(itB, kh0A, kl0A, kh1A, kl1A, kh0B, kl0B, kh1B, kl1B);
    }
    ATTN_PHASE(30, kh0B, kl0B, kh1B, kl1B, kh0A, kl0A, kh1A, kl1A);
#undef ATTN_PHASE

    // epilogue: PV(31) from plds/vlds buffer 1
    {
        short8 pf0 = *(const short8*)(pr0 + 8192);
        short8 pf1 = *(const short8*)(pr1 + 8192);
        short8 vf[8];
#pragma unroll
        for (int dt = 0; dt < 8; ++dt)
            vf[dt] = *(const short8*)(vlds[1] + vro + dt * 1024);
#pragma unroll
        for (int dt = 0; dt < 8; ++dt) {
            acc[0][dt] = __builtin_amdgcn_mfma_f32_16x16x32_bf16(vf[dt], pf0, acc[0][dt], 0, 0, 0);
            acc[1][dt] = __builtin_amdgcn_mfma_f32_16x16x32_bf16(vf[dt], pf1, acc[1][dt], 0, 0, 0);
        }
    }

    // l reduction across the 4 g-groups (own q-subtile only)
    l_run += __shfl_xor(l_run, 16); l_run += __shfl_xor(l_run, 32);

    // dump raw partials, coalesced: per (qs,dt) one 1KB wave-store of a
    // 16q x 16d tile in [q][d] order at f32 offset col*16 + g*4.
    float* op = O_part + (size_t)bid * 32768 + wave * 4096;
#pragma unroll
    for (int qs = 0; qs < 2; ++qs)
#pragma unroll
        for (int dt = 0; dt < 8; ++dt) {
            int j = qs * 8 + dt;
            *(f32x4*)(op + j * 256 + col * 16 + g * 4) = acc[qs][dt];
        }
    if (g == 0)   // wave (qq,dh) owns lsum slot qs=dh of its quarter
        lsum_part[bid * 128 + qq * 32 + dh * 16 + col] = l_run;
}

// ---------------------------------------------------------------------------
// Kernel 3: epilogue. out[b,s,k,d] = gamma * (sum_ks O_part)/(sum_ks l) + x.
// ---------------------------------------------------------------------------
__global__ __launch_bounds__(256) void epi_kernel(
    const float* __restrict__ O_part, const float* __restrict__ lsum_part,
    const float* __restrict__ x, const float* __restrict__ gamma_p,
    float* __restrict__ out)
{
    int gid = blockIdx.x * 256 + threadIdx.x;   // 0..524287
    int d  = (gid & 63) * 4;
    int nl = gid >> 6;
    int b  = nl >> 12;
    int n  = nl & (N_ - 1);

    int qt = n >> 7, qq = (n >> 5) & 3, qs = (n >> 4) & 1, col = n & 15;
    int dh = d >> 7, dt = (d >> 4) & 7;
    int w = qq * 2 + dh, j = qs * 8 + dt;
    int boff = w * 4096 + j * 256 + col * 16 + (d & 15);
    int loff = qq * 32 + qs * 16 + col;

    f32x4 acc = {0.f, 0.f, 0.f, 0.f};
    float l = 0.f;
#pragma unroll
    for (int ks = 0; ks < 4; ++ks) {
        int bid = qt * 8 + b * 4 + ks;
        f32x4 p = *(const f32x4*)(O_part + (size_t)bid * 32768 + boff);
        acc[0] += p[0]; acc[1] += p[1]; acc[2] += p[2]; acc[3] += p[3];
        l += lsum_part[bid * 128 + loff];
    }
    float scale = gamma_p[0] / l;
    int s = n & 63, kk = n >> 6;
    size_t o = (((size_t)(b * S_ + s)) * K_ + kk) * D_ + d;
    f32x4 xv = *(const f32x4*)(x + o);
    f32x4 ov;
#pragma unroll
    for (int e = 0; e < 4; ++e) ov[e] = acc[e] * scale + xv[e];
    *(f32x4*)(out + o) = ov;
}

extern "C" void kernel_launch(void* const* d_in, const int* in_sizes, int n_in,
                              void* d_out, int out_size, void* d_ws, size_t ws_size,
                              hipStream_t stream) {
    const float* x  = (const float*)d_in[0];
    const float* Wq = (const float*)d_in[1];
    const float* bq = (const float*)d_in[2];
    const float* Wk = (const float*)d_in[3];
    const float* bk = (const float*)d_in[4];
    const float* Wv = (const float*)d_in[5];
    const float* bv = (const float*)d_in[6];
    const float* gm = (const float*)d_in[7];

    char* ws = (char*)d_ws;
    unsigned short* Wh   = (unsigned short*)(ws);                 // 160KB
    unsigned short* Wl   = (unsigned short*)(ws + 0x40000);       // 160KB
    float*          bcat = (float*)         (ws + 0x80000);       // 1.3KB
    unsigned short* Qh   = (unsigned short*)(ws + 0x100000);      // 512KB
    unsigned short* Ql   = (unsigned short*)(ws + 0x180000);
    unsigned short* Kh   = (unsigned short*)(ws + 0x200000);
    unsigned short* Kl   = (unsigned short*)(ws + 0x280000);
    unsigned short* Vm   = (unsigned short*)(ws + 0x300000);      // 4MB
    float*          Op   = (float*)         (ws + 0x700000);      // 32MB
    float*          lp   = (float*)         (ws + 0x2700000);     // 128KB
    float* o = (float*)d_out;

    wcvt_kernel<<<320, 256, 0, stream>>>(Wq, bq, Wk, bk, Wv, bv, Wh, Wl, bcat);
    qkv_kernel<<<512, 256, 0, stream>>>(x, Wh, Wl, bcat, Qh, Ql, Kh, Kl, Vm);
    attn_kernel<<<256, 512, 0, stream>>>(Qh, Ql, Kh, Kl, Vm, Op, lp);
    epi_kernel<<<2048, 256, 0, stream>>>(Op, lp, x, gm, o);
}

// Round 18
// 68.406 us; speedup vs baseline: 5.9288x; 1.0151x over previous
//
#include <hip/hip_runtime.h>
#include <stdint.h>
#include <math.h>

using short8   = __attribute__((ext_vector_type(8))) short;
using ushort4v = __attribute__((ext_vector_type(4))) unsigned short;
using f32x4    = __attribute__((ext_vector_type(4))) float;
using uint4v   = __attribute__((ext_vector_type(4))) unsigned int;
using uint2v   = __attribute__((ext_vector_type(2))) unsigned int;

#define B_ 2
#define S_ 64
#define K_ 64
#define D_ 256
#define C_ 32
#define N_ 4096  /* S_*K_ */
#define LOG2E 1.4426950408889634f

__device__ __forceinline__ float b2f(unsigned short u) {
    unsigned int v = ((unsigned int)u) << 16;
    return __builtin_bit_cast(float, v);
}
__device__ __forceinline__ unsigned short f2b(float f) {   // RNE f32->bf16
    unsigned int x = __builtin_bit_cast(unsigned int, f);
    x += 0x7fffu + ((x >> 16) & 1u);
    return (unsigned short)(x >> 16);
}
// pack two f32 -> bf16x2 (a low, b high), RNE, pure ALU (m240)
__device__ __forceinline__ unsigned int pk2(float a, float b) {
    unsigned int xa = __builtin_bit_cast(unsigned int, a);
    unsigned int xb = __builtin_bit_cast(unsigned int, b);
    xa += 0x7fffu + ((xa >> 16) & 1u);
    xb += 0x7fffu + ((xb >> 16) & 1u);
    return (xa >> 16) | (xb & 0xffff0000u);
}

// ---------------------------------------------------------------------------
// Kernel 0: W/bias pre-convert. oc 0-31 Q (x log2e), 32-63 K, 64-319 V.
// ---------------------------------------------------------------------------
__global__ __launch_bounds__(256) void wcvt_kernel(
    const float* __restrict__ Wq, const float* __restrict__ bq,
    const float* __restrict__ Wk, const float* __restrict__ bk,
    const float* __restrict__ Wv, const float* __restrict__ bv,
    unsigned short* __restrict__ Wh, unsigned short* __restrict__ Wl,
    float* __restrict__ bcat)
{
    int oc = blockIdx.x;            // 0..319
    int d  = threadIdx.x;           // 0..255
    float w;
    if (oc < 32)       w = Wq[oc * 256 + d] * LOG2E;
    else if (oc < 64)  w = Wk[(oc - 32) * 256 + d];
    else               w = Wv[(oc - 64) * 256 + d];
    unsigned short h = f2b(w);
    Wh[oc * 256 + d] = h;
    Wl[oc * 256 + d] = f2b(w - b2f(h));
    if (d == 0) {
        float bb;
        if (oc < 32)      bb = bq[oc] * LOG2E;
        else if (oc < 64) bb = bk[oc - 32];
        else              bb = bv[oc - 64];
        bcat[oc] = bb;
    }
}

// ---------------------------------------------------------------------------
// Kernel 1: QKV projections (verified). Q,K [B][N][C] hi/lo. V chunk-
// interleaved [B][N/32][D*32]: slot-permuted in-chunk token order
// (s = 8*((j&15)>>2) + ((j&16)>>2) + (j&3)) + byte XOR swizzle
// o ^= (d&7)<<4 within the 16KB chunk (bank-balance for attn's LDS path).
// ---------------------------------------------------------------------------
__global__ __launch_bounds__(256) void qkv_kernel(
    const float* __restrict__ x,
    const unsigned short* __restrict__ Wh, const unsigned short* __restrict__ Wl,
    const float* __restrict__ bcat,
    unsigned short* __restrict__ Qh, unsigned short* __restrict__ Ql,
    unsigned short* __restrict__ Kh, unsigned short* __restrict__ Kl,
    unsigned short* __restrict__ Vm)
{
    __shared__ unsigned short lxh[16 * 256];   // [tok][d] bf16-hi, swizzled
    __shared__ unsigned short lxl[16 * 256];   // bf16-lo

    int tid = threadIdx.x;
    int bid = blockIdx.x;
    int b  = bid >> 8;
    int n0 = (bid & 255) << 4;

    {
        int tt = tid >> 4, dg0 = (tid & 15) * 16;
        int n = n0 + tt;
        int s = n & 63, kk = n >> 6;
        const float* xr = x + (((size_t)(b * S_ + s)) * K_ + kk) * D_ + dg0;
        short8 h0, l0, h1, l1;
#pragma unroll
        for (int e = 0; e < 8; ++e) {
            float v = xr[e];
            unsigned short hh = f2b(v);
            h0[e] = (short)hh; l0[e] = (short)f2b(v - b2f(hh));
        }
#pragma unroll
        for (int e = 0; e < 8; ++e) {
            float v = xr[8 + e];
            unsigned short hh = f2b(v);
            h1[e] = (short)hh; l1[e] = (short)f2b(v - b2f(hh));
        }
        int m0 = dg0 >> 3;
        int sw0 = ((m0 ^ (tt & 7)) << 3);
        int sw1 = (((m0 + 1) ^ (tt & 7)) << 3);
        *(short8*)(lxh + tt * 256 + sw0) = h0;
        *(short8*)(lxh + tt * 256 + sw1) = h1;
        *(short8*)(lxl + tt * 256 + sw0) = l0;
        *(short8*)(lxl + tt * 256 + sw1) = l1;
    }
    __syncthreads();

    int wave = tid >> 6, lane = tid & 63;
    int col = lane & 15, g = lane >> 4;

#pragma unroll
    for (int i = 0; i < 5; ++i) {
        int ct = wave + i * 4;                   // 0..19
        int oc0 = ct * 16;
        const unsigned short* whr = Wh + (size_t)(oc0 + col) * 256;
        const unsigned short* wlr = Wl + (size_t)(oc0 + col) * 256;
        f32x4 acc = {0.f, 0.f, 0.f, 0.f};

        if (ct < 4) {                            // Q/K: split-bf16 3-chain
#pragma unroll
            for (int dc = 0; dc < 8; ++dc) {
                int sw = (((dc * 4 + g) ^ (col & 7)) << 3);
                short8 xh8 = *(const short8*)(lxh + col * 256 + sw);
                short8 xl8 = *(const short8*)(lxl + col * 256 + sw);
                short8 wh8 = *(const short8*)(whr + dc * 32 + g * 8);
                short8 wl8 = *(const short8*)(wlr + dc * 32 + g * 8);
                acc = __builtin_amdgcn_mfma_f32_16x16x32_bf16(xl8, wh8, acc, 0, 0, 0);
                acc = __builtin_amdgcn_mfma_f32_16x16x32_bf16(xh8, wl8, acc, 0, 0, 0);
                acc = __builtin_amdgcn_mfma_f32_16x16x32_bf16(xh8, wh8, acc, 0, 0, 0);
            }
            float bb = bcat[oc0 + col];
            unsigned short* Th = (ct < 2) ? Qh : Kh;
            unsigned short* Tl = (ct < 2) ? Ql : Kl;
            int c0 = (ct & 1) * 16;
#pragma unroll
            for (int r = 0; r < 4; ++r) {
                int tok = n0 + g * 4 + r;
                float v = acc[r] + bb;
                unsigned short hh = f2b(v);
                size_t idx = ((size_t)b * N_ + tok) * C_ + c0 + col;
                Th[idx] = hh;
                Tl[idx] = f2b(v - b2f(hh));
            }
        } else {                                 // V: single bf16
#pragma unroll
            for (int dc = 0; dc < 8; ++dc) {
                int sw = (((dc * 4 + g) ^ (col & 7)) << 3);
                short8 xh8 = *(const short8*)(lxh + col * 256 + sw);
                short8 wh8 = *(const short8*)(whr + dc * 32 + g * 8);
                acc = __builtin_amdgcn_mfma_f32_16x16x32_bf16(xh8, wh8, acc, 0, 0, 0);
            }
            float bb = bcat[oc0 + col];
            int c0 = oc0 - 64;
            ushort4v st;
#pragma unroll
            for (int r = 0; r < 4; ++r) st[r] = f2b(acc[r] + bb);
            int tok0 = n0 + g * 4;
            int s0 = 8 * g + ((n0 & 16) >> 2);   // slot-permuted in-chunk pos
            int d_ch = c0 + col;
            int o = d_ch * 64 + s0 * 2;          // byte offset within 16KB chunk
            o ^= (d_ch & 7) << 4;                // bank-swizzle (8B-run safe)
            size_t vbyteoff = ((size_t)b * (N_ / 32) + (tok0 >> 5)) * (D_ * 32 * 2)
                            + (size_t)o;
            *(ushort4v*)((char*)Vm + vbyteoff) = st;
        }
    }
}

// ---------------------------------------------------------------------------
// Kernel 2: flash attention, 16-wave / 4-waves-per-SIMD version (R13 done
// right). 256 blocks x 1024 threads, __launch_bounds__(1024,4): 128-unified-
// reg cap, met by halving per-wave state: acc[2 subtile][4 dt] = 32 AGPR
// (wave owns a d-QUARTER dq*64), QK role quartered (wave computes its qq's
// scores for subtile qs_own=dq>>1 x key-half kh=dq&1 -> 3 MFMA, all 4
// combos covered exactly once, zero duplication). V-through-LDS + skewed
// P-exchange as R16/R17; vf still amortized over both subtiles (LDS-read
// volume unchanged). O_part dump arranged so epi layout is IDENTICAL
// (w = qq*2 + dq>>1, j = qs*8 + (dq&1)*4 + dt); lsum gains a kh plane.
// ---------------------------------------------------------------------------
__global__ __launch_bounds__(1024, 4) void attn_kernel(
    const unsigned short* __restrict__ Qh, const unsigned short* __restrict__ Ql,
    const unsigned short* __restrict__ Kh, const unsigned short* __restrict__ Kl,
    const unsigned short* __restrict__ Vm,
    float* __restrict__ O_part, float* __restrict__ lsum_part)
{
    __shared__ __align__(16) char vlds[2][16384];   // V chunk double-buffer
    __shared__ __align__(16) char plds[2 * 8192];   // P exchange double-buffer

    int tid  = threadIdx.x;
    int wave = tid >> 6;          // 0..15
    int lane = tid & 63;
    int col = lane & 15, g = lane >> 4;
    int qq = wave >> 2;           // q-quarter 0..3
    int dq = wave & 3;            // d-quarter 0..3
    int kh = dq & 1;              // produced key-half
    int qs_own = dq >> 1;         // produced q-subtile
    int tid16 = tid * 16;
    int lane16 = lane * 16;

    int bid = blockIdx.x;
    int x7 = bid & 7;
    int b  = x7 >> 2;
    int ks = x7 & 3;
    int qt = bid >> 3;            // 0..31 (q-tile within batch)
    int q0 = qt * 128 + qq * 32;
    int jbase = ks * (N_ / 4);

    // Q fragments for OWN produced subtile only
    size_t qoff = ((size_t)b * N_ + q0 + qs_own * 16 + col) * C_ + g * 8;
    short8 qfh = *(const short8*)(Qh + qoff);
    short8 qfl = *(const short8*)(Ql + qoff);

    f32x4 acc[2][4];
#pragma unroll
    for (int qs = 0; qs < 2; ++qs)
#pragma unroll
        for (int dt = 0; dt < 4; ++dt) acc[qs][dt] = (f32x4){0.f, 0.f, 0.f, 0.f};
    float l_run = 0.f;

    const unsigned short* kbh = Kh + (size_t)b * N_ * C_;
    const unsigned short* kbl = Kl + (size_t)b * N_ * C_;
    const char* vbyte = (const char*)Vm + (size_t)b * ((size_t)N_ * D_ * 2);

    auto kaddr = [&](int it) {
        return (size_t)(jbase + it * 32 + kh * 16 + col) * C_ + g * 8;
    };

    // lane-constant swizzled ds_read offset for V fragments (d-quarter dq)
    unsigned vro = (unsigned)(((dq * 64 + col) * 64 + g * 16) ^ ((col & 7) << 4));
    int st = qq * 2 + qs_own;
    char* pmy = plds + st * 1024 + lane16 + kh * 8;       // own 8B publish slot
    const char* pr0 = plds + (qq * 2) * 1024 + lane16;     // subtile 0 read
    const char* pr1 = plds + (qq * 2 + 1) * 1024 + lane16; // subtile 1 read

    // ---- prologue: stage V(0); K(0)->A, K(1)->B; QK(0) -> plds buf0 ----
    {
        const char* vsrc = vbyte + (size_t)(ks * 32) * 16384 + tid16;
        *(f32x4*)(vlds[0] + tid16) = *(const f32x4*)(vsrc);
    }
    short8 khA = *(const short8*)(kbh + kaddr(0));
    short8 klA = *(const short8*)(kbl + kaddr(0));
    short8 khB = *(const short8*)(kbh + kaddr(1));
    short8 klB = *(const short8*)(kbl + kaddr(1));
    {
        f32x4 z = {0.f, 0.f, 0.f, 0.f};
        f32x4 sa = __builtin_amdgcn_mfma_f32_16x16x32_bf16(klA, qfh, z, 0, 0, 0);
        sa = __builtin_amdgcn_mfma_f32_16x16x32_bf16(khA, qfl, sa, 0, 0, 0);
        sa = __builtin_amdgcn_mfma_f32_16x16x32_bf16(khA, qfh, sa, 0, 0, 0);
        float pa[4];
#pragma unroll
        for (int r = 0; r < 4; ++r) pa[r] = exp2f(sa[r]);
        l_run += (pa[0] + pa[1]) + (pa[2] + pa[3]);
        uint2v uo;
        uo[0] = pk2(pa[0], pa[1]); uo[1] = pk2(pa[2], pa[3]);
        *(uint2v*)(pmy) = uo;   // buffer 0
    }
    __syncthreads();

    // phase IT: stage V(IT+1), prefetch K(IT+2), QK(IT+1) own quarter (CUR
    // set), PV(IT) from plds/vlds[IT&1], publish P+V, barrier.
#define ATTN_PHASE(IT, CKH, CKL, NKH, NKL)                                       \
    {                                                                            \
        int itn_ = (IT) + 1;                                                     \
        int itk_ = (IT) + 2;  /* may run past end: wrap-free, discarded */       \
        const char* vsrc_ = vbyte + (size_t)(ks * 32 + itn_) * 16384 + tid16;    \
        f32x4 stg_ = *(const f32x4*)(vsrc_);                                     \
        NKH = *(const short8*)(kbh + kaddr(itk_));                               \
        NKL = *(const short8*)(kbl + kaddr(itk_));                               \
        __builtin_amdgcn_sched_barrier(0);  /* loads stay issued up here */      \
        f32x4 z_ = {0.f, 0.f, 0.f, 0.f};                                         \
        f32x4 sa_ = __builtin_amdgcn_mfma_f32_16x16x32_bf16(CKL, qfh, z_, 0, 0, 0); \
        sa_ = __builtin_amdgcn_mfma_f32_16x16x32_bf16(CKH, qfl, sa_, 0, 0, 0);   \
        sa_ = __builtin_amdgcn_mfma_f32_16x16x32_bf16(CKH, qfh, sa_, 0, 0, 0);   \
        float pa_[4];                                                            \
        _Pragma("unroll")                                                        \
        for (int r = 0; r < 4; ++r) pa_[r] = exp2f(sa_[r]);                      \
        l_run += (pa_[0] + pa_[1]) + (pa_[2] + pa_[3]);                          \
        uint2v uo_;                                                              \
        uo_[0] = pk2(pa_[0], pa_[1]); uo_[1] = pk2(pa_[2], pa_[3]);              \
        int rb_ = (IT) & 1, wb_ = (itn_) & 1;                                    \
        short8 pf0_ = *(const short8*)(pr0 + rb_ * 8192);                        \
        short8 pf1_ = *(const short8*)(pr1 + rb_ * 8192);                        \
        short8 vf_[4];                                                           \
        _Pragma("unroll")                                                        \
        for (int dt = 0; dt < 4; ++dt)                                           \
            vf_[dt] = *(const short8*)(vlds[rb_] + vro + dt * 1024);             \
        _Pragma("unroll")                                                        \
        for (int dt = 0; dt < 4; ++dt) {                                         \
            acc[0][dt] = __builtin_amdgcn_mfma_f32_16x16x32_bf16(vf_[dt], pf0_, acc[0][dt], 0, 0, 0); \
            acc[1][dt] = __builtin_amdgcn_mfma_f32_16x16x32_bf16(vf_[dt], pf1_, acc[1][dt], 0, 0, 0); \
        }                                                                        \
        *(uint2v*)(pmy + wb_ * 8192) = uo_;                                      \
        *(f32x4*)(vlds[wb_] + tid16) = stg_;                                     \
        __syncthreads();                                                         \
    }

    for (int it2 = 0; it2 < 15; ++it2) {
        int itA = it2 * 2, itB = itA + 1;
        ATTN_PHASE(itA, khB, klB, khA, klA);
        ATTN_PHASE(itB, khA, klA, khB, klB);
    }
    ATTN_PHASE(30, khB, klB, khA, klA);
#undef ATTN_PHASE

    // epilogue: PV(31) from plds/vlds buffer 1
    {
        short8 pf0 = *(const short8*)(pr0 + 8192);
        short8 pf1 = *(const short8*)(pr1 + 8192);
        short8 vf[4];
#pragma unroll
        for (int dt = 0; dt < 4; ++dt)
            vf[dt] = *(const short8*)(vlds[1] + vro + dt * 1024);
#pragma unroll
        for (int dt = 0; dt < 4; ++dt) {
            acc[0][dt] = __builtin_amdgcn_mfma_f32_16x16x32_bf16(vf[dt], pf0, acc[0][dt], 0, 0, 0);
            acc[1][dt] = __builtin_amdgcn_mfma_f32_16x16x32_bf16(vf[dt], pf1, acc[1][dt], 0, 0, 0);
        }
    }

    // l reduction across the 4 g-groups (own subtile x own key-half)
    l_run += __shfl_xor(l_run, 16); l_run += __shfl_xor(l_run, 32);

    // dump raw partials, epi-compatible layout: w = qq*2 + (dq>>1),
    // j = qs*8 + (dq&1)*4 + dt, element = col*16 + g*4.
    float* op = O_part + (size_t)bid * 32768 + (qq * 2 + (dq >> 1)) * 4096;
#pragma unroll
    for (int qs = 0; qs < 2; ++qs)
#pragma unroll
        for (int dt = 0; dt < 4; ++dt) {
            int j = qs * 8 + (dq & 1) * 4 + dt;
            *(f32x4*)(op + j * 256 + col * 16 + g * 4) = acc[qs][dt];
        }
    if (g == 0)   // wave owns lsum slot (kh plane, qq, qs_own)
        lsum_part[bid * 256 + kh * 128 + qq * 32 + qs_own * 16 + col] = l_run;
}

// ---------------------------------------------------------------------------
// Kernel 3: epilogue. out[b,s,k,d] = gamma * (sum_ks O_part)/(sum_ks l) + x.
// (l now summed over the two key-half planes as well.)
// ---------------------------------------------------------------------------
__global__ __launch_bounds__(256) void epi_kernel(
    const float* __restrict__ O_part, const float* __restrict__ lsum_part,
    const float* __restrict__ x, const float* __restrict__ gamma_p,
    float* __restrict__ out)
{
    int gid = blockIdx.x * 256 + threadIdx.x;   // 0..524287
    int d  = (gid & 63) * 4;
    int nl = gid >> 6;
    int b  = nl >> 12;
    int n  = nl & (N_ - 1);

    int qt = n >> 7, qq = (n >> 5) & 3, qs = (n >> 4) & 1, col = n & 15;
    int dh = d >> 7, dt = (d >> 4) & 7;
    int w = qq * 2 + dh, j = qs * 8 + dt;
    int boff = w * 4096 + j * 256 + col * 16 + (d & 15);
    int loff = qq * 32 + qs * 16 + col;

    f32x4 acc = {0.f, 0.f, 0.f, 0.f};
    float l = 0.f;
#pragma unroll
    for (int ks = 0; ks < 4; ++ks) {
        int bid = qt * 8 + b * 4 + ks;
        f32x4 p = *(const f32x4*)(O_part + (size_t)bid * 32768 + boff);
        acc[0] += p[0]; acc[1] += p[1]; acc[2] += p[2]; acc[3] += p[3];
        l += lsum_part[bid * 256 + loff] + lsum_part[bid * 256 + 128 + loff];
    }
    float scale = gamma_p[0] / l;
    int s = n & 63, kk = n >> 6;
    size_t o = (((size_t)(b * S_ + s)) * K_ + kk) * D_ + d;
    f32x4 xv = *(const f32x4*)(x + o);
    f32x4 ov;
#pragma unroll
    for (int e = 0; e < 4; ++e) ov[e] = acc[e] * scale + xv[e];
    *(f32x4*)(out + o) = ov;
}

extern "C" void kernel_launch(void* const* d_in, const int* in_sizes, int n_in,
                              void* d_out, int out_size, void* d_ws, size_t ws_size,
                              hipStream_t stream) {
    const float* x  = (const float*)d_in[0];
    const float* Wq = (const float*)d_in[1];
    const float* bq = (const float*)d_in[2];
    const float* Wk = (const float*)d_in[3];
    const float* bk = (const float*)d_in[4];
    const float* Wv = (const float*)d_in[5];
    const float* bv = (const float*)d_in[6];
    const float* gm = (const float*)d_in[7];

    char* ws = (char*)d_ws;
    unsigned short* Wh   = (unsigned short*)(ws);                 // 160KB
    unsigned short* Wl   = (unsigned short*)(ws + 0x40000);       // 160KB
    float*          bcat = (float*)         (ws + 0x80000);       // 1.3KB
    unsigned short* Qh   = (unsigned short*)(ws + 0x100000);      // 512KB
    unsigned short* Ql   = (unsigned short*)(ws + 0x180000);
    unsigned short* Kh   = (unsigned short*)(ws + 0x200000);
    unsigned short* Kl   = (unsigned short*)(ws + 0x280000);
    unsigned short* Vm   = (unsigned short*)(ws + 0x300000);      // 4MB
    float*          Op   = (float*)         (ws + 0x700000);      // 32MB
    float*          lp   = (float*)         (ws + 0x2700000);     // 256KB
    float* o = (float*)d_out;

    wcvt_kernel<<<320, 256, 0, stream>>>(Wq, bq, Wk, bk, Wv, bv, Wh, Wl, bcat);
    qkv_kernel<<<512, 256, 0, stream>>>(x, Wh, Wl, bcat, Qh, Ql, Kh, Kl, Vm);
    attn_kernel<<<256, 1024, 0, stream>>>(Qh, Ql, Kh, Kl, Vm, Op, lp);
    epi_kernel<<<2048, 256, 0, stream>>>(Op, lp, x, gm, o);
}

// Round 19
// 62.974 us; speedup vs baseline: 6.4402x; 1.0863x over previous
//
#include <hip/hip_runtime.h>
#include <stdint.h>
#include <math.h>

using short8   = __attribute__((ext_vector_type(8))) short;
using ushort4v = __attribute__((ext_vector_type(4))) unsigned short;
using f32x4    = __attribute__((ext_vector_type(4))) float;
using uint4v   = __attribute__((ext_vector_type(4))) unsigned int;
using uint2v   = __attribute__((ext_vector_type(2))) unsigned int;

#define B_ 2
#define S_ 64
#define K_ 64
#define D_ 256
#define C_ 32
#define N_ 4096  /* S_*K_ */
#define LOG2E 1.4426950408889634f

__device__ __forceinline__ float b2f(unsigned short u) {
    unsigned int v = ((unsigned int)u) << 16;
    return __builtin_bit_cast(float, v);
}
__device__ __forceinline__ unsigned short f2b(float f) {   // RNE f32->bf16
    unsigned int x = __builtin_bit_cast(unsigned int, f);
    x += 0x7fffu + ((x >> 16) & 1u);
    return (unsigned short)(x >> 16);
}
// pack two f32 -> bf16x2 (a low, b high), RNE, pure ALU (m240)
__device__ __forceinline__ unsigned int pk2(float a, float b) {
    unsigned int xa = __builtin_bit_cast(unsigned int, a);
    unsigned int xb = __builtin_bit_cast(unsigned int, b);
    xa += 0x7fffu + ((xa >> 16) & 1u);
    xb += 0x7fffu + ((xb >> 16) & 1u);
    return (xa >> 16) | (xb & 0xffff0000u);
}

// ---------------------------------------------------------------------------
// Kernel 0: W/bias pre-convert. oc 0-31 Q (x log2e), 32-63 K, 64-319 V.
// ---------------------------------------------------------------------------
__global__ __launch_bounds__(256) void wcvt_kernel(
    const float* __restrict__ Wq, const float* __restrict__ bq,
    const float* __restrict__ Wk, const float* __restrict__ bk,
    const float* __restrict__ Wv, const float* __restrict__ bv,
    unsigned short* __restrict__ Wh, unsigned short* __restrict__ Wl,
    float* __restrict__ bcat)
{
    int oc = blockIdx.x;            // 0..319
    int d  = threadIdx.x;           // 0..255
    float w;
    if (oc < 32)       w = Wq[oc * 256 + d] * LOG2E;
    else if (oc < 64)  w = Wk[(oc - 32) * 256 + d];
    else               w = Wv[(oc - 64) * 256 + d];
    unsigned short h = f2b(w);
    Wh[oc * 256 + d] = h;
    Wl[oc * 256 + d] = f2b(w - b2f(h));
    if (d == 0) {
        float bb;
        if (oc < 32)      bb = bq[oc] * LOG2E;
        else if (oc < 64) bb = bk[oc - 32];
        else              bb = bv[oc - 64];
        bcat[oc] = bb;
    }
}

// ---------------------------------------------------------------------------
// Kernel 1: QKV projections (verified, unchanged). Q,K [B][N][C] hi/lo.
// V chunk-interleaved [B][N/32][D*32]: slot-permuted in-chunk token order
// (s = 8*((j&15)>>2) + ((j&16)>>2) + (j&3)) + byte XOR swizzle
// o ^= (d&7)<<4 within the 16KB chunk (bank-balance for attn's LDS path).
// ---------------------------------------------------------------------------
__global__ __launch_bounds__(256) void qkv_kernel(
    const float* __restrict__ x,
    const unsigned short* __restrict__ Wh, const unsigned short* __restrict__ Wl,
    const float* __restrict__ bcat,
    unsigned short* __restrict__ Qh, unsigned short* __restrict__ Ql,
    unsigned short* __restrict__ Kh, unsigned short* __restrict__ Kl,
    unsigned short* __restrict__ Vm)
{
    __shared__ unsigned short lxh[16 * 256];   // [tok][d] bf16-hi, swizzled
    __shared__ unsigned short lxl[16 * 256];   // bf16-lo

    int tid = threadIdx.x;
    int bid = blockIdx.x;
    int b  = bid >> 8;
    int n0 = (bid & 255) << 4;

    {
        int tt = tid >> 4, dg0 = (tid & 15) * 16;
        int n = n0 + tt;
        int s = n & 63, kk = n >> 6;
        const float* xr = x + (((size_t)(b * S_ + s)) * K_ + kk) * D_ + dg0;
        short8 h0, l0, h1, l1;
#pragma unroll
        for (int e = 0; e < 8; ++e) {
            float v = xr[e];
            unsigned short hh = f2b(v);
            h0[e] = (short)hh; l0[e] = (short)f2b(v - b2f(hh));
        }
#pragma unroll
        for (int e = 0; e < 8; ++e) {
            float v = xr[8 + e];
            unsigned short hh = f2b(v);
            h1[e] = (short)hh; l1[e] = (short)f2b(v - b2f(hh));
        }
        int m0 = dg0 >> 3;
        int sw0 = ((m0 ^ (tt & 7)) << 3);
        int sw1 = (((m0 + 1) ^ (tt & 7)) << 3);
        *(short8*)(lxh + tt * 256 + sw0) = h0;
        *(short8*)(lxh + tt * 256 + sw1) = h1;
        *(short8*)(lxl + tt * 256 + sw0) = l0;
        *(short8*)(lxl + tt * 256 + sw1) = l1;
    }
    __syncthreads();

    int wave = tid >> 6, lane = tid & 63;
    int col = lane & 15, g = lane >> 4;

#pragma unroll
    for (int i = 0; i < 5; ++i) {
        int ct = wave + i * 4;                   // 0..19
        int oc0 = ct * 16;
        const unsigned short* whr = Wh + (size_t)(oc0 + col) * 256;
        const unsigned short* wlr = Wl + (size_t)(oc0 + col) * 256;
        f32x4 acc = {0.f, 0.f, 0.f, 0.f};

        if (ct < 4) {                            // Q/K: split-bf16 3-chain
#pragma unroll
            for (int dc = 0; dc < 8; ++dc) {
                int sw = (((dc * 4 + g) ^ (col & 7)) << 3);
                short8 xh8 = *(const short8*)(lxh + col * 256 + sw);
                short8 xl8 = *(const short8*)(lxl + col * 256 + sw);
                short8 wh8 = *(const short8*)(whr + dc * 32 + g * 8);
                short8 wl8 = *(const short8*)(wlr + dc * 32 + g * 8);
                acc = __builtin_amdgcn_mfma_f32_16x16x32_bf16(xl8, wh8, acc, 0, 0, 0);
                acc = __builtin_amdgcn_mfma_f32_16x16x32_bf16(xh8, wl8, acc, 0, 0, 0);
                acc = __builtin_amdgcn_mfma_f32_16x16x32_bf16(xh8, wh8, acc, 0, 0, 0);
            }
            float bb = bcat[oc0 + col];
            unsigned short* Th = (ct < 2) ? Qh : Kh;
            unsigned short* Tl = (ct < 2) ? Ql : Kl;
            int c0 = (ct & 1) * 16;
#pragma unroll
            for (int r = 0; r < 4; ++r) {
                int tok = n0 + g * 4 + r;
                float v = acc[r] + bb;
                unsigned short hh = f2b(v);
                size_t idx = ((size_t)b * N_ + tok) * C_ + c0 + col;
                Th[idx] = hh;
                Tl[idx] = f2b(v - b2f(hh));
            }
        } else {                                 // V: single bf16
#pragma unroll
            for (int dc = 0; dc < 8; ++dc) {
                int sw = (((dc * 4 + g) ^ (col & 7)) << 3);
                short8 xh8 = *(const short8*)(lxh + col * 256 + sw);
                short8 wh8 = *(const short8*)(whr + dc * 32 + g * 8);
                acc = __builtin_amdgcn_mfma_f32_16x16x32_bf16(xh8, wh8, acc, 0, 0, 0);
            }
            float bb = bcat[oc0 + col];
            int c0 = oc0 - 64;
            ushort4v st;
#pragma unroll
            for (int r = 0; r < 4; ++r) st[r] = f2b(acc[r] + bb);
            int tok0 = n0 + g * 4;
            int s0 = 8 * g + ((n0 & 16) >> 2);   // slot-permuted in-chunk pos
            int d_ch = c0 + col;
            int o = d_ch * 64 + s0 * 2;          // byte offset within 16KB chunk
            o ^= (d_ch & 7) << 4;                // bank-swizzle (8B-run safe)
            size_t vbyteoff = ((size_t)b * (N_ / 32) + (tok0 >> 5)) * (D_ * 32 * 2)
                            + (size_t)o;
            *(ushort4v*)((char*)Vm + vbyteoff) = st;
        }
    }
}

// ---------------------------------------------------------------------------
// Kernel 2: flash attention (R18 verified structure: 16 waves, quartered QK
// role, V-through-LDS + skewed P-exchange). NEW: (a) O_part dumped as BF16
// (half the write+epi-read traffic; partials have 2x error headroom),
// (b) T5 s_setprio(1) around the QK and PV MFMA clusters (phase-split
// schedule = the regime where setprio pays, m191/m218b).
// ---------------------------------------------------------------------------
__global__ __launch_bounds__(1024, 4) void attn_kernel(
    const unsigned short* __restrict__ Qh, const unsigned short* __restrict__ Ql,
    const unsigned short* __restrict__ Kh, const unsigned short* __restrict__ Kl,
    const unsigned short* __restrict__ Vm,
    unsigned short* __restrict__ O_bf16, float* __restrict__ lsum_part)
{
    __shared__ __align__(16) char vlds[2][16384];   // V chunk double-buffer
    __shared__ __align__(16) char plds[2 * 8192];   // P exchange double-buffer

    int tid  = threadIdx.x;
    int wave = tid >> 6;          // 0..15
    int lane = tid & 63;
    int col = lane & 15, g = lane >> 4;
    int qq = wave >> 2;           // q-quarter 0..3
    int dq = wave & 3;            // d-quarter 0..3
    int kh = dq & 1;              // produced key-half
    int qs_own = dq >> 1;         // produced q-subtile
    int tid16 = tid * 16;
    int lane16 = lane * 16;

    int bid = blockIdx.x;
    int x7 = bid & 7;
    int b  = x7 >> 2;
    int ks = x7 & 3;
    int qt = bid >> 3;            // 0..31 (q-tile within batch)
    int q0 = qt * 128 + qq * 32;
    int jbase = ks * (N_ / 4);

    // Q fragments for OWN produced subtile only
    size_t qoff = ((size_t)b * N_ + q0 + qs_own * 16 + col) * C_ + g * 8;
    short8 qfh = *(const short8*)(Qh + qoff);
    short8 qfl = *(const short8*)(Ql + qoff);

    f32x4 acc[2][4];
#pragma unroll
    for (int qs = 0; qs < 2; ++qs)
#pragma unroll
        for (int dt = 0; dt < 4; ++dt) acc[qs][dt] = (f32x4){0.f, 0.f, 0.f, 0.f};
    float l_run = 0.f;

    const unsigned short* kbh = Kh + (size_t)b * N_ * C_;
    const unsigned short* kbl = Kl + (size_t)b * N_ * C_;
    const char* vbyte = (const char*)Vm + (size_t)b * ((size_t)N_ * D_ * 2);

    auto kaddr = [&](int it) {
        return (size_t)(jbase + it * 32 + kh * 16 + col) * C_ + g * 8;
    };

    // lane-constant swizzled ds_read offset for V fragments (d-quarter dq)
    unsigned vro = (unsigned)(((dq * 64 + col) * 64 + g * 16) ^ ((col & 7) << 4));
    int st = qq * 2 + qs_own;
    char* pmy = plds + st * 1024 + lane16 + kh * 8;       // own 8B publish slot
    const char* pr0 = plds + (qq * 2) * 1024 + lane16;     // subtile 0 read
    const char* pr1 = plds + (qq * 2 + 1) * 1024 + lane16; // subtile 1 read

    // ---- prologue: stage V(0); K(0)->A, K(1)->B; QK(0) -> plds buf0 ----
    {
        const char* vsrc = vbyte + (size_t)(ks * 32) * 16384 + tid16;
        *(f32x4*)(vlds[0] + tid16) = *(const f32x4*)(vsrc);
    }
    short8 khA = *(const short8*)(kbh + kaddr(0));
    short8 klA = *(const short8*)(kbl + kaddr(0));
    short8 khB = *(const short8*)(kbh + kaddr(1));
    short8 klB = *(const short8*)(kbl + kaddr(1));
    {
        f32x4 z = {0.f, 0.f, 0.f, 0.f};
        f32x4 sa = __builtin_amdgcn_mfma_f32_16x16x32_bf16(klA, qfh, z, 0, 0, 0);
        sa = __builtin_amdgcn_mfma_f32_16x16x32_bf16(khA, qfl, sa, 0, 0, 0);
        sa = __builtin_amdgcn_mfma_f32_16x16x32_bf16(khA, qfh, sa, 0, 0, 0);
        float pa[4];
#pragma unroll
        for (int r = 0; r < 4; ++r) pa[r] = exp2f(sa[r]);
        l_run += (pa[0] + pa[1]) + (pa[2] + pa[3]);
        uint2v uo;
        uo[0] = pk2(pa[0], pa[1]); uo[1] = pk2(pa[2], pa[3]);
        *(uint2v*)(pmy) = uo;   // buffer 0
    }
    __syncthreads();

    // phase IT: stage V(IT+1), prefetch K(IT+2), QK(IT+1) own quarter (CUR
    // set), PV(IT) from plds/vlds[IT&1], publish P+V, barrier.
#define ATTN_PHASE(IT, CKH, CKL, NKH, NKL)                                       \
    {                                                                            \
        int itn_ = (IT) + 1;                                                     \
        int itk_ = (IT) + 2;  /* may run past end: wrap-free, discarded */       \
        const char* vsrc_ = vbyte + (size_t)(ks * 32 + itn_) * 16384 + tid16;    \
        f32x4 stg_ = *(const f32x4*)(vsrc_);                                     \
        NKH = *(const short8*)(kbh + kaddr(itk_));                               \
        NKL = *(const short8*)(kbl + kaddr(itk_));                               \
        __builtin_amdgcn_sched_barrier(0);  /* loads stay issued up here */      \
        f32x4 z_ = {0.f, 0.f, 0.f, 0.f};                                         \
        __builtin_amdgcn_s_setprio(1);                                           \
        f32x4 sa_ = __builtin_amdgcn_mfma_f32_16x16x32_bf16(CKL, qfh, z_, 0, 0, 0); \
        sa_ = __builtin_amdgcn_mfma_f32_16x16x32_bf16(CKH, qfl, sa_, 0, 0, 0);   \
        sa_ = __builtin_amdgcn_mfma_f32_16x16x32_bf16(CKH, qfh, sa_, 0, 0, 0);   \
        __builtin_amdgcn_s_setprio(0);                                           \
        float pa_[4];                                                            \
        _Pragma("unroll")                                                        \
        for (int r = 0; r < 4; ++r) pa_[r] = exp2f(sa_[r]);                      \
        l_run += (pa_[0] + pa_[1]) + (pa_[2] + pa_[3]);                          \
        uint2v uo_;                                                              \
        uo_[0] = pk2(pa_[0], pa_[1]); uo_[1] = pk2(pa_[2], pa_[3]);              \
        int rb_ = (IT) & 1, wb_ = (itn_) & 1;                                    \
        short8 pf0_ = *(const short8*)(pr0 + rb_ * 8192);                        \
        short8 pf1_ = *(const short8*)(pr1 + rb_ * 8192);                        \
        short8 vf_[4];                                                           \
        _Pragma("unroll")                                                        \
        for (int dt = 0; dt < 4; ++dt)                                           \
            vf_[dt] = *(const short8*)(vlds[rb_] + vro + dt * 1024);             \
        __builtin_amdgcn_s_setprio(1);                                           \
        _Pragma("unroll")                                                        \
        for (int dt = 0; dt < 4; ++dt) {                                         \
            acc[0][dt] = __builtin_amdgcn_mfma_f32_16x16x32_bf16(vf_[dt], pf0_, acc[0][dt], 0, 0, 0); \
            acc[1][dt] = __builtin_amdgcn_mfma_f32_16x16x32_bf16(vf_[dt], pf1_, acc[1][dt], 0, 0, 0); \
        }                                                                        \
        __builtin_amdgcn_s_setprio(0);                                           \
        *(uint2v*)(pmy + wb_ * 8192) = uo_;                                      \
        *(f32x4*)(vlds[wb_] + tid16) = stg_;                                     \
        __syncthreads();                                                         \
    }

    for (int it2 = 0; it2 < 15; ++it2) {
        int itA = it2 * 2, itB = itA + 1;
        ATTN_PHASE(itA, khB, klB, khA, klA);
        ATTN_PHASE(itB, khA, klA, khB, klB);
    }
    ATTN_PHASE(30, khB, klB, khA, klA);
#undef ATTN_PHASE

    // epilogue: PV(31) from plds/vlds buffer 1
    {
        short8 pf0 = *(const short8*)(pr0 + 8192);
        short8 pf1 = *(const short8*)(pr1 + 8192);
        short8 vf[4];
#pragma unroll
        for (int dt = 0; dt < 4; ++dt)
            vf[dt] = *(const short8*)(vlds[1] + vro + dt * 1024);
#pragma unroll
        for (int dt = 0; dt < 4; ++dt) {
            acc[0][dt] = __builtin_amdgcn_mfma_f32_16x16x32_bf16(vf[dt], pf0, acc[0][dt], 0, 0, 0);
            acc[1][dt] = __builtin_amdgcn_mfma_f32_16x16x32_bf16(vf[dt], pf1, acc[1][dt], 0, 0, 0);
        }
    }

    // l reduction across the 4 g-groups (own subtile x own key-half)
    l_run += __shfl_xor(l_run, 16); l_run += __shfl_xor(l_run, 32);

    // dump partials as BF16, epi-compatible element layout: w = qq*2+(dq>>1),
    // j = qs*8 + (dq&1)*4 + dt, element = col*16 + g*4 (ushort units).
    unsigned short* op = O_bf16 + (size_t)bid * 32768 + (qq * 2 + (dq >> 1)) * 4096;
#pragma unroll
    for (int qs = 0; qs < 2; ++qs)
#pragma unroll
        for (int dt = 0; dt < 4; ++dt) {
            int j = qs * 8 + (dq & 1) * 4 + dt;
            uint2v uo;
            uo[0] = pk2(acc[qs][dt][0], acc[qs][dt][1]);
            uo[1] = pk2(acc[qs][dt][2], acc[qs][dt][3]);
            *(uint2v*)(op + j * 256 + col * 16 + g * 4) = uo;
        }
    if (g == 0)   // wave owns lsum slot (kh plane, qq, qs_own)
        lsum_part[bid * 256 + kh * 128 + qq * 32 + qs_own * 16 + col] = l_run;
}

// ---------------------------------------------------------------------------
// Kernel 3: epilogue. out[b,s,k,d] = gamma * (sum_ks O)/(sum_ks l) + x.
// O_part now bf16 (same element-unit layout); l summed over kh planes.
// ---------------------------------------------------------------------------
__global__ __launch_bounds__(256) void epi_kernel(
    const unsigned short* __restrict__ O_bf16, const float* __restrict__ lsum_part,
    const float* __restrict__ x, const float* __restrict__ gamma_p,
    float* __restrict__ out)
{
    int gid = blockIdx.x * 256 + threadIdx.x;   // 0..524287
    int d  = (gid & 63) * 4;
    int nl = gid >> 6;
    int b  = nl >> 12;
    int n  = nl & (N_ - 1);

    int qt = n >> 7, qq = (n >> 5) & 3, qs = (n >> 4) & 1, col = n & 15;
    int dh = d >> 7, dt = (d >> 4) & 7;
    int w = qq * 2 + dh, j = qs * 8 + dt;
    int boff = w * 4096 + j * 256 + col * 16 + (d & 15);
    int loff = qq * 32 + qs * 16 + col;

    f32x4 acc = {0.f, 0.f, 0.f, 0.f};
    float l = 0.f;
#pragma unroll
    for (int ks = 0; ks < 4; ++ks) {
        int bid = qt * 8 + b * 4 + ks;
        ushort4v p = *(const ushort4v*)(O_bf16 + (size_t)bid * 32768 + boff);
        acc[0] += b2f(p[0]); acc[1] += b2f(p[1]);
        acc[2] += b2f(p[2]); acc[3] += b2f(p[3]);
        l += lsum_part[bid * 256 + loff] + lsum_part[bid * 256 + 128 + loff];
    }
    float scale = gamma_p[0] / l;
    int s = n & 63, kk = n >> 6;
    size_t o = (((size_t)(b * S_ + s)) * K_ + kk) * D_ + d;
    f32x4 xv = *(const f32x4*)(x + o);
    f32x4 ov;
#pragma unroll
    for (int e = 0; e < 4; ++e) ov[e] = acc[e] * scale + xv[e];
    *(f32x4*)(out + o) = ov;
}

extern "C" void kernel_launch(void* const* d_in, const int* in_sizes, int n_in,
                              void* d_out, int out_size, void* d_ws, size_t ws_size,
                              hipStream_t stream) {
    const float* x  = (const float*)d_in[0];
    const float* Wq = (const float*)d_in[1];
    const float* bq = (const float*)d_in[2];
    const float* Wk = (const float*)d_in[3];
    const float* bk = (const float*)d_in[4];
    const float* Wv = (const float*)d_in[5];
    const float* bv = (const float*)d_in[6];
    const float* gm = (const float*)d_in[7];

    char* ws = (char*)d_ws;
    unsigned short* Wh   = (unsigned short*)(ws);                 // 160KB
    unsigned short* Wl   = (unsigned short*)(ws + 0x40000);       // 160KB
    float*          bcat = (float*)         (ws + 0x80000);       // 1.3KB
    unsigned short* Qh   = (unsigned short*)(ws + 0x100000);      // 512KB
    unsigned short* Ql   = (unsigned short*)(ws + 0x180000);
    unsigned short* Kh   = (unsigned short*)(ws + 0x200000);
    unsigned short* Kl   = (unsigned short*)(ws + 0x280000);
    unsigned short* Vm   = (unsigned short*)(ws + 0x300000);      // 4MB
    unsigned short* Op   = (unsigned short*)(ws + 0x700000);      // 16MB (bf16)
    float*          lp   = (float*)         (ws + 0x2700000);     // 256KB
    float* o = (float*)d_out;

    wcvt_kernel<<<320, 256, 0, stream>>>(Wq, bq, Wk, bk, Wv, bv, Wh, Wl, bcat);
    qkv_kernel<<<512, 256, 0, stream>>>(x, Wh, Wl, bcat, Qh, Ql, Kh, Kl, Vm);
    attn_kernel<<<256, 1024, 0, stream>>>(Qh, Ql, Kh, Kl, Vm, Op, lp);
    epi_kernel<<<2048, 256, 0, stream>>>(Op, lp, x, gm, o);
}